// Round 7
// baseline (234192.065 us; speedup 1.0000x reference)
//
#include <hip/hip_runtime.h>
#include <math.h>

#define T 16384

typedef float f32x4  __attribute__((ext_vector_type(4)));
typedef float f32x16 __attribute__((ext_vector_type(16)));

__device__ __forceinline__ float softplusf_(float x) {
    return (x > 15.f) ? x : __logf(1.f + __expf(x));
}
__device__ __forceinline__ float sigmoidf_(float x) {
    return 1.f / (1.f + __expf(-x));
}
__device__ __forceinline__ float tanh_fast(float x) {
    float xc = fminf(fmaxf(x, -15.f), 15.f);
    float e = __expf(2.f * xc);
    return (e - 1.f) / (e + 1.f);
}

// ---- AGPR stash primitives (gfx90a+/gfx950 unified file; 'a' = AGPR class) ----
#define AGW1(dst, val) asm volatile("v_accvgpr_write_b32 %0, %1" : "=a"(dst) : "v"(val))
#define AGR1(dst, src) asm volatile("v_accvgpr_read_b32 %0, %1" : "=v"(dst) : "a"(src))
#define DECL4(P) float P##_0, P##_1, P##_2, P##_3

#define PARK_WEH(KQ) do{ \
  AGW1(weh##KQ##_0, Wenc[(129+4*KQ+0)*256+j]); \
  AGW1(weh##KQ##_1, Wenc[(129+4*KQ+1)*256+j]); \
  AGW1(weh##KQ##_2, Wenc[(129+4*KQ+2)*256+j]); \
  AGW1(weh##KQ##_3, Wenc[(129+4*KQ+3)*256+j]); }while(0)

#define PARK_WMA(KQ) do{ \
  AGW1(wmA##KQ##_0, Wm[(cA4*64+((4*KQ+0+8*cA4)&63))*64+m4]); \
  AGW1(wmA##KQ##_1, Wm[(cA4*64+((4*KQ+1+8*cA4)&63))*64+m4]); \
  AGW1(wmA##KQ##_2, Wm[(cA4*64+((4*KQ+2+8*cA4)&63))*64+m4]); \
  AGW1(wmA##KQ##_3, Wm[(cA4*64+((4*KQ+3+8*cA4)&63))*64+m4]); }while(0)

#define PARK_WMB(KQ) do{ \
  AGW1(wmB##KQ##_0, Wm[(cB4*64+((4*KQ+0+8*cB4)&63))*64+m4]); \
  AGW1(wmB##KQ##_1, Wm[(cB4*64+((4*KQ+1+8*cB4)&63))*64+m4]); \
  AGW1(wmB##KQ##_2, Wm[(cB4*64+((4*KQ+2+8*cB4)&63))*64+m4]); \
  AGW1(wmB##KQ##_3, Wm[(cB4*64+((4*KQ+3+8*cB4)&63))*64+m4]); }while(0)

// S1+S3 fused iteration (unlabeled): q-dot from LDS wq4, eh-dot from AGPR weh
#define S13U(KQ,P0,P1,P2,P3,Q0,Q1,Q2,Q3) do{ \
  f32x4 h_ = hb4[KQ]; f32x4 w_ = wq4[KQ][j]; \
  float u0,u1,u2,u3; \
  AGR1(u0, weh##KQ##_0); AGR1(u1, weh##KQ##_1); \
  AGR1(u2, weh##KQ##_2); AGR1(u3, weh##KQ##_3); \
  P0=fmaf(h_[0],w_[0],P0); P1=fmaf(h_[1],w_[1],P1); \
  P2=fmaf(h_[2],w_[2],P2); P3=fmaf(h_[3],w_[3],P3); \
  Q0=fmaf(h_[0],u0,Q0); Q1=fmaf(h_[1],u1,Q1); \
  Q2=fmaf(h_[2],u2,Q2); Q3=fmaf(h_[3],u3,Q3); }while(0)

// S3-only iteration (labeled)
#define S13L(KQ,Q0,Q1,Q2,Q3) do{ \
  f32x4 h_ = hb4[KQ]; float u0,u1,u2,u3; \
  AGR1(u0, weh##KQ##_0); AGR1(u1, weh##KQ##_1); \
  AGR1(u2, weh##KQ##_2); AGR1(u3, weh##KQ##_3); \
  Q0=fmaf(h_[0],u0,Q0); Q1=fmaf(h_[1],u1,Q1); \
  Q2=fmaf(h_[2],u2,Q2); Q3=fmaf(h_[3],u3,Q3); }while(0)

#define S4A(KQ,P0,P1,P2,P3) do{ \
  f32x4 e_ = eb4[cA4*16+KQ]; float u0,u1,u2,u3; \
  AGR1(u0, wmA##KQ##_0); AGR1(u1, wmA##KQ##_1); \
  AGR1(u2, wmA##KQ##_2); AGR1(u3, wmA##KQ##_3); \
  P0=fmaf(e_[0],u0,P0); P1=fmaf(e_[1],u1,P1); \
  P2=fmaf(e_[2],u2,P2); P3=fmaf(e_[3],u3,P3); }while(0)

#define S4B(KQ,P0,P1,P2,P3) do{ \
  f32x4 e_ = eb4[cB4*16+KQ]; float u0,u1,u2,u3; \
  AGR1(u0, wmB##KQ##_0); AGR1(u1, wmB##KQ##_1); \
  AGR1(u2, wmB##KQ##_2); AGR1(u3, wmB##KQ##_3); \
  P0=fmaf(e_[0],u0,P0); P1=fmaf(e_[1],u1,P1); \
  P2=fmaf(e_[2],u2,P2); P3=fmaf(e_[3],u3,P3); }while(0)

// S4B from a VGPR-resident group (the 2 groups left out of AGPR)
#define S4BV(V,KQ,P0,P1,P2,P3) do{ \
  f32x4 e_ = eb4[cB4*16+KQ]; \
  P0=fmaf(e_[0],V[0],P0); P1=fmaf(e_[1],V[1],P1); \
  P2=fmaf(e_[2],V[2],P2); P3=fmaf(e_[3],V[3],P3); }while(0)

// ---------------------------------------------------------------------------
// Precompute x-dependent matvec parts + logit(eps_u) (fully parallel).
// ---------------------------------------------------------------------------
__global__ __launch_bounds__(256) void k_pre(
    const float* __restrict__ x, const float* __restrict__ eu_g,
    const float* __restrict__ Wqy, const float* __restrict__ Wenc,
    const float* __restrict__ Wih,
    float* __restrict__ Aq, float* __restrict__ Ae, float* __restrict__ Ah,
    float* __restrict__ leu_g)
{
    __shared__ float xs[16 * 128];
    const int t0 = blockIdx.x * 16;
    for (int r = threadIdx.x; r < 16 * 128; r += 256) xs[r] = x[t0 * 128 + r];
    __syncthreads();
    const int j = threadIdx.x;
    if (j < 16) {
        float eu = eu_g[t0 + j];
        leu_g[t0 + j] = __logf(eu) - __logf(1.f - eu);
    }
    for (int tt = 0; tt < 16; ++tt) {
        float aq = 0.f, ae = 0.f;
#pragma unroll 8
        for (int i = 0; i < 128; ++i) {
            float xv = xs[tt * 128 + i];
            aq = fmaf(xv, Wqy[i * 256 + j], aq);
            ae = fmaf(xv, Wenc[i * 256 + j], ae);
        }
        Aq[(size_t)(t0 + tt) * 256 + j] = aq;
        Ae[(size_t)(t0 + tt) * 256 + j] = ae;
    }
    if (j < 128) {
        for (int tt = 0; tt < 16; ++tt) {
            float ah = 0.f;
#pragma unroll 8
            for (int i = 0; i < 128; ++i)
                ah = fmaf(xs[tt * 128 + i], Wih[(65 + i) * 128 + j], ah);
            Ah[(size_t)(t0 + tt) * 128 + j] = ah;
        }
    }
}

// ---------------------------------------------------------------------------
// Sequential scan. 1 block, 256 threads (4 waves, 1/SIMD -> 512 unified regs
// per wave). weh(128f)+wms(120f) parked in AGPRs (248); S5 weights + temps in
// arch VGPRs (~200 < 256, no spill). Arithmetic bit-identical to round 6.
// ---------------------------------------------------------------------------
__global__
__attribute__((amdgpu_flat_work_group_size(256, 256)))
__attribute__((amdgpu_waves_per_eu(1, 1)))
void k_scan(
    const float* __restrict__ Wqy, const float* __restrict__ qpr,
    const float* __restrict__ Wenc,
    const float* __restrict__ Wem0, const float* __restrict__ Wes0,
    const float* __restrict__ Wih, const float* __restrict__ Whh,
    const float* __restrict__ yin_g, const float* __restrict__ leu_g,
    const float* __restrict__ ez_g,
    const float* __restrict__ Aq, const float* __restrict__ Ae,
    const float* __restrict__ Ah,
    float* __restrict__ h_st, float* __restrict__ z_st,
    float* __restrict__ em_st, float* __restrict__ es_st,
    float* __restrict__ y_st)
{
    const int tid = threadIdx.x;
    const int j   = tid;                       // S1/S3: one output per thread
    const int m4  = tid >> 2, k4 = (tid >> 1) & 1, c4n = tid & 1;   // S4
    const int o5  = tid >> 1, c5n = tid & 1;                        // S5
    const int cA4 = 2 * c4n, cB4 = 2 * c4n + 1;    // S4 original chunk ids
    const int XA  = 2 * c5n, XB = 2 * c5n + 1;     // S5 original chunk ids

    // rotated-storage positions (write side) for ehR / hR
    const int cR = j >> 6;
    const int pR = cR * 64 + (((j & 63) - 8 * cR) & 63);
    const int oX = o5 >> 5;
    const int pH = oX * 32 + (((o5 & 31) - 8 * oX) & 31);

    // ---- LDS ----
    __shared__ __align__(16) f32x4 wq4[32][256];     // 128 KB: W_q_y h-part
    __shared__ __align__(16) float s_aq[4][256];
    __shared__ __align__(16) float s_ae[4][256];
    __shared__ __align__(16) float s_ah[4][128];
    __shared__ __align__(16) float s_ez[4][64];
    __shared__ __align__(16) float s_yin[4];
    __shared__ __align__(16) float s_leu[4];
    __shared__ __align__(16) float t_h[4][128];
    __shared__ __align__(16) float t_z[4][64];
    __shared__ __align__(16) float t_em[4][64];
    __shared__ __align__(16) float t_es[4][64];
    __shared__ float t_y[4];
    __shared__ __align__(16) float h_lds[2][128];
    __shared__ __align__(16) float hR[2][128];       // rot-stored h for S5
    __shared__ __align__(16) float ehR[256];         // rot-stored eh for S4
    __shared__ __align__(16) float z_lds[64];
    __shared__ float red2[4];

    // ---- AGPR-parked weights: weh groups 0..31, wmA 0..15, wmB 0..13 ----
    DECL4(weh0);  DECL4(weh1);  DECL4(weh2);  DECL4(weh3);
    DECL4(weh4);  DECL4(weh5);  DECL4(weh6);  DECL4(weh7);
    DECL4(weh8);  DECL4(weh9);  DECL4(weh10); DECL4(weh11);
    DECL4(weh12); DECL4(weh13); DECL4(weh14); DECL4(weh15);
    DECL4(weh16); DECL4(weh17); DECL4(weh18); DECL4(weh19);
    DECL4(weh20); DECL4(weh21); DECL4(weh22); DECL4(weh23);
    DECL4(weh24); DECL4(weh25); DECL4(weh26); DECL4(weh27);
    DECL4(weh28); DECL4(weh29); DECL4(weh30); DECL4(weh31);
    DECL4(wmA0);  DECL4(wmA1);  DECL4(wmA2);  DECL4(wmA3);
    DECL4(wmA4);  DECL4(wmA5);  DECL4(wmA6);  DECL4(wmA7);
    DECL4(wmA8);  DECL4(wmA9);  DECL4(wmA10); DECL4(wmA11);
    DECL4(wmA12); DECL4(wmA13); DECL4(wmA14); DECL4(wmA15);
    DECL4(wmB0);  DECL4(wmB1);  DECL4(wmB2);  DECL4(wmB3);
    DECL4(wmB4);  DECL4(wmB5);  DECL4(wmB6);  DECL4(wmB7);
    DECL4(wmB8);  DECL4(wmB9);  DECL4(wmB10); DECL4(wmB11);
    DECL4(wmB12); DECL4(wmB13);

    PARK_WEH(0);  PARK_WEH(1);  PARK_WEH(2);  PARK_WEH(3);
    PARK_WEH(4);  PARK_WEH(5);  PARK_WEH(6);  PARK_WEH(7);
    PARK_WEH(8);  PARK_WEH(9);  PARK_WEH(10); PARK_WEH(11);
    PARK_WEH(12); PARK_WEH(13); PARK_WEH(14); PARK_WEH(15);
    PARK_WEH(16); PARK_WEH(17); PARK_WEH(18); PARK_WEH(19);
    PARK_WEH(20); PARK_WEH(21); PARK_WEH(22); PARK_WEH(23);
    PARK_WEH(24); PARK_WEH(25); PARK_WEH(26); PARK_WEH(27);
    PARK_WEH(28); PARK_WEH(29); PARK_WEH(30); PARK_WEH(31);

    const float wey = Wenc[128 * 256 + j];
    const float qpj = qpr[j];

    {
        const float* Wm = k4 ? Wes0 : Wem0;
        PARK_WMA(0);  PARK_WMA(1);  PARK_WMA(2);  PARK_WMA(3);
        PARK_WMA(4);  PARK_WMA(5);  PARK_WMA(6);  PARK_WMA(7);
        PARK_WMA(8);  PARK_WMA(9);  PARK_WMA(10); PARK_WMA(11);
        PARK_WMA(12); PARK_WMA(13); PARK_WMA(14); PARK_WMA(15);
        PARK_WMB(0);  PARK_WMB(1);  PARK_WMB(2);  PARK_WMB(3);
        PARK_WMB(4);  PARK_WMB(5);  PARK_WMB(6);  PARK_WMB(7);
        PARK_WMB(8);  PARK_WMB(9);  PARK_WMB(10); PARK_WMB(11);
        PARK_WMB(12); PARK_WMB(13);
    }
    // last 2 wmB groups stay in arch VGPRs (leave 8 AGPRs spare for safety)
    f32x4 wmB14v, wmB15v;
    {
        const float* Wm = k4 ? Wes0 : Wem0;
#pragma unroll
        for (int e = 0; e < 4; ++e) {
            wmB14v[e] = Wm[(cB4 * 64 + ((4 * 14 + e + 8 * cB4) & 63)) * 64 + m4];
            wmB15v[e] = Wm[(cB4 * 64 + ((4 * 15 + e + 8 * cB4) & 63)) * 64 + m4];
        }
    }

    // S5 weights in arch VGPRs (96 floats)
    f32x16 wzA, wzB, whA[2], whB[2];
#pragma unroll
    for (int e = 0; e < 16; ++e) {
        wzA[e] = Wih[(1 + XA * 16 + e) * 128 + o5];
        wzB[e] = Wih[(1 + XB * 16 + e) * 128 + o5];
    }
#pragma unroll
    for (int v = 0; v < 2; ++v)
#pragma unroll
        for (int e = 0; e < 16; ++e) {
            int k = 16 * v + e;
            whA[v][e] = Whh[(XA * 32 + ((k + 8 * XA) & 31)) * 128 + o5];
            whB[v][e] = Whh[(XB * 32 + ((k + 8 * XB) & 31)) * 128 + o5];
        }
    const float wihy = Wih[o5];

    // W_q_y h-part -> LDS [32][256] (col j per thread)
#pragma unroll 4
    for (int kq = 0; kq < 32; ++kq) {
        f32x4 v;
        v[0] = Wqy[(128 + 4 * kq + 0) * 256 + j];
        v[1] = Wqy[(128 + 4 * kq + 1) * 256 + j];
        v[2] = Wqy[(128 + 4 * kq + 2) * 256 + j];
        v[3] = Wqy[(128 + 4 * kq + 3) * 256 + j];
        wq4[kq][j] = v;
    }
    if (tid < 128) {
        h_lds[0][tid] = 0.f;
        hR[0][tid] = 0.f;
    }

    // ---- staging: global -> regs (early) -> LDS (late) ----
    f32x4 pA, pB, pC;
    auto load_regs = [&](int t0) {
        pA = ((const f32x4*)(Aq + (size_t)t0 * 256))[tid];
        pB = ((const f32x4*)(Ae + (size_t)t0 * 256))[tid];
        if (tid < 128)       pC = ((const f32x4*)(Ah + (size_t)t0 * 128))[tid];
        else if (tid < 192)  pC = ((const f32x4*)(ez_g + (size_t)t0 * 64))[tid - 128];
        else if (tid == 192) pC = *(const f32x4*)(yin_g + t0);
        else if (tid == 193) pC = *(const f32x4*)(leu_g + t0);
    };
    auto write_regs = [&]() {
        ((f32x4*)&s_aq[0][0])[tid] = pA;
        ((f32x4*)&s_ae[0][0])[tid] = pB;
        if (tid < 128)       ((f32x4*)&s_ah[0][0])[tid] = pC;
        else if (tid < 192)  ((f32x4*)&s_ez[0][0])[tid - 128] = pC;
        else if (tid == 192) *(f32x4*)s_yin = pC;
        else if (tid == 193) *(f32x4*)s_leu = pC;
    };
    auto flushb = [&](int t0) {
        if (tid < 64)
            ((f32x4*)(es_st + (size_t)t0 * 64))[tid] = ((const f32x4*)&t_es[0][0])[tid];
        if (tid < 128) {
            ((f32x4*)(h_st + (size_t)t0 * 128))[tid] = ((const f32x4*)&t_h[0][0])[tid];
        } else if (tid < 192) {
            ((f32x4*)(z_st + (size_t)t0 * 64))[tid - 128] = ((const f32x4*)&t_z[0][0])[tid - 128];
        } else {
            ((f32x4*)(em_st + (size_t)t0 * 64))[tid - 192] = ((const f32x4*)&t_em[0][0])[tid - 192];
        }
        if (tid >= 252) y_st[t0 + (tid - 252)] = t_y[tid - 252];
    };

    load_regs(0);
    write_regs();
    __syncthreads();

    for (int t0 = 0; t0 < T; t0 += 4) {
        const int tnb = (t0 + 4 < T) ? t0 + 4 : t0;
        load_regs(tnb);                                // issue early (T14)

        for (int tt = 0; tt < 4; ++tt) {
            const int t = t0 + tt;
            const int cur = t & 1, nxt = cur ^ 1;
            const float aq  = s_aq[tt][j];
            const float ae  = s_ae[tt][j];
            const float yin = s_yin[tt];
            const float leu = s_leu[tt];
            const float ez  = s_ez[tt][m4];
            const float ah  = s_ah[tt][o5];
            const f32x4* __restrict__ hb4 = (const f32x4*)&h_lds[cur][0];

            float y_t, ehdot;
            if (yin == -1.0f) {
                float a0 = 0.f, a1 = 0.f, a2 = 0.f, a3 = 0.f;
                float A0 = 0.f, A1 = 0.f, A2 = 0.f, A3 = 0.f;
                float e0 = 0.f, e1 = 0.f, e2 = 0.f, e3 = 0.f;
                float E0 = 0.f, E1 = 0.f, E2 = 0.f, E3 = 0.f;
                S13U(0,a0,a1,a2,a3,e0,e1,e2,e3);  S13U(1,a0,a1,a2,a3,e0,e1,e2,e3);
                S13U(2,a0,a1,a2,a3,e0,e1,e2,e3);  S13U(3,a0,a1,a2,a3,e0,e1,e2,e3);
                S13U(4,a0,a1,a2,a3,e0,e1,e2,e3);  S13U(5,a0,a1,a2,a3,e0,e1,e2,e3);
                S13U(6,a0,a1,a2,a3,e0,e1,e2,e3);  S13U(7,a0,a1,a2,a3,e0,e1,e2,e3);
                S13U(8,a0,a1,a2,a3,e0,e1,e2,e3);  S13U(9,a0,a1,a2,a3,e0,e1,e2,e3);
                S13U(10,a0,a1,a2,a3,e0,e1,e2,e3); S13U(11,a0,a1,a2,a3,e0,e1,e2,e3);
                S13U(12,a0,a1,a2,a3,e0,e1,e2,e3); S13U(13,a0,a1,a2,a3,e0,e1,e2,e3);
                S13U(14,a0,a1,a2,a3,e0,e1,e2,e3); S13U(15,a0,a1,a2,a3,e0,e1,e2,e3);
                S13U(16,A0,A1,A2,A3,E0,E1,E2,E3); S13U(17,A0,A1,A2,A3,E0,E1,E2,E3);
                S13U(18,A0,A1,A2,A3,E0,E1,E2,E3); S13U(19,A0,A1,A2,A3,E0,E1,E2,E3);
                S13U(20,A0,A1,A2,A3,E0,E1,E2,E3); S13U(21,A0,A1,A2,A3,E0,E1,E2,E3);
                S13U(22,A0,A1,A2,A3,E0,E1,E2,E3); S13U(23,A0,A1,A2,A3,E0,E1,E2,E3);
                S13U(24,A0,A1,A2,A3,E0,E1,E2,E3); S13U(25,A0,A1,A2,A3,E0,E1,E2,E3);
                S13U(26,A0,A1,A2,A3,E0,E1,E2,E3); S13U(27,A0,A1,A2,A3,E0,E1,E2,E3);
                S13U(28,A0,A1,A2,A3,E0,E1,E2,E3); S13U(29,A0,A1,A2,A3,E0,E1,E2,E3);
                S13U(30,A0,A1,A2,A3,E0,E1,E2,E3); S13U(31,A0,A1,A2,A3,E0,E1,E2,E3);
                float sQ = ((a0 + a1) + (a2 + a3)) + ((A0 + A1) + (A2 + A3));
                ehdot    = ((e0 + e1) + (e2 + e3)) + ((E0 + E1) + (E2 + E3));
                float qh = fmaxf(aq + sQ, 0.f);
                float cq = qh * qpj;
#pragma unroll
                for (int d = 1; d < 64; d <<= 1) cq += __shfl_xor(cq, d);
                if ((tid & 63) == 0) red2[tid >> 6] = cq;
                __syncthreads();                           // B1
                float qlog = (red2[0] + red2[1]) + (red2[2] + red2[3]);
                y_t = sigmoidf_(leu + qlog);
            } else {
                float e0 = 0.f, e1 = 0.f, e2 = 0.f, e3 = 0.f;
                float E0 = 0.f, E1 = 0.f, E2 = 0.f, E3 = 0.f;
                S13L(0,e0,e1,e2,e3);  S13L(1,e0,e1,e2,e3);
                S13L(2,e0,e1,e2,e3);  S13L(3,e0,e1,e2,e3);
                S13L(4,e0,e1,e2,e3);  S13L(5,e0,e1,e2,e3);
                S13L(6,e0,e1,e2,e3);  S13L(7,e0,e1,e2,e3);
                S13L(8,e0,e1,e2,e3);  S13L(9,e0,e1,e2,e3);
                S13L(10,e0,e1,e2,e3); S13L(11,e0,e1,e2,e3);
                S13L(12,e0,e1,e2,e3); S13L(13,e0,e1,e2,e3);
                S13L(14,e0,e1,e2,e3); S13L(15,e0,e1,e2,e3);
                S13L(16,E0,E1,E2,E3); S13L(17,E0,E1,E2,E3);
                S13L(18,E0,E1,E2,E3); S13L(19,E0,E1,E2,E3);
                S13L(20,E0,E1,E2,E3); S13L(21,E0,E1,E2,E3);
                S13L(22,E0,E1,E2,E3); S13L(23,E0,E1,E2,E3);
                S13L(24,E0,E1,E2,E3); S13L(25,E0,E1,E2,E3);
                S13L(26,E0,E1,E2,E3); S13L(27,E0,E1,E2,E3);
                S13L(28,E0,E1,E2,E3); S13L(29,E0,E1,E2,E3);
                S13L(30,E0,E1,E2,E3); S13L(31,E0,E1,E2,E3);
                ehdot = ((e0 + e1) + (e2 + e3)) + ((E0 + E1) + (E2 + E3));
                y_t = yin;
            }

            // S3 finalize: eh = relu(Ae + y*wey + h-dot); write rotated copy
            {
                float eh = fmaxf(fmaf(y_t, wey, ae) + ehdot, 0.f);
                ehR[pR] = eh;
            }
            __syncthreads();                               // B3

            // S4: em/es over eh(256), 2 sub-chunks
            {
                const f32x4* __restrict__ eb4 = (const f32x4*)ehR;
                float b0 = 0.f, b1 = 0.f, b2 = 0.f, b3 = 0.f;
                float B0 = 0.f, B1v = 0.f, B2 = 0.f, B3 = 0.f;
                S4A(0,b0,b1,b2,b3);  S4A(1,b0,b1,b2,b3);
                S4A(2,b0,b1,b2,b3);  S4A(3,b0,b1,b2,b3);
                S4A(4,b0,b1,b2,b3);  S4A(5,b0,b1,b2,b3);
                S4A(6,b0,b1,b2,b3);  S4A(7,b0,b1,b2,b3);
                S4A(8,b0,b1,b2,b3);  S4A(9,b0,b1,b2,b3);
                S4A(10,b0,b1,b2,b3); S4A(11,b0,b1,b2,b3);
                S4A(12,b0,b1,b2,b3); S4A(13,b0,b1,b2,b3);
                S4A(14,b0,b1,b2,b3); S4A(15,b0,b1,b2,b3);
                S4B(0,B0,B1v,B2,B3);  S4B(1,B0,B1v,B2,B3);
                S4B(2,B0,B1v,B2,B3);  S4B(3,B0,B1v,B2,B3);
                S4B(4,B0,B1v,B2,B3);  S4B(5,B0,B1v,B2,B3);
                S4B(6,B0,B1v,B2,B3);  S4B(7,B0,B1v,B2,B3);
                S4B(8,B0,B1v,B2,B3);  S4B(9,B0,B1v,B2,B3);
                S4B(10,B0,B1v,B2,B3); S4B(11,B0,B1v,B2,B3);
                S4B(12,B0,B1v,B2,B3); S4B(13,B0,B1v,B2,B3);
                S4BV(wmB14v,14,B0,B1v,B2,B3);
                S4BV(wmB15v,15,B0,B1v,B2,B3);
                float s = ((b0 + b1) + (b2 + b3)) + ((B0 + B1v) + (B2 + B3));
                s += __shfl_xor(s, 1);                     // combine c4n
                float other = __shfl_xor(s, 2);            // k4 partner
                float em_pre = k4 ? other : s;
                float es_pre = k4 ? s : other;
                float es = softplusf_(es_pre);
                float zm = fmaf(ez, es, em_pre);
                if ((tid & 3) == 0) {
                    z_lds[m4] = zm;
                    t_z[tt][m4] = zm; t_em[tt][m4] = em_pre; t_es[tt][m4] = es;
                }
            }
            __syncthreads();                               // B4

            // S5: h_new = tanh(Ah + y*wihy + z@Wih_z + h@W_hh), 2 sub-chunks
            {
                const f32x4* __restrict__ zb4 = (const f32x4*)z_lds;
                const f32x4* __restrict__ hR4 = (const f32x4*)&hR[cur][0];
                float g0 = 0.f, g1 = 0.f, g2 = 0.f, g3 = 0.f;
                float G0 = 0.f, G1 = 0.f, G2 = 0.f, G3 = 0.f;
#pragma unroll
                for (int kq = 0; kq < 4; ++kq) {           // z part, chunk A
                    f32x4 zv = zb4[XA * 4 + kq];
                    g0 = fmaf(zv[0], wzA[4 * kq + 0], g0);
                    g1 = fmaf(zv[1], wzA[4 * kq + 1], g1);
                    g2 = fmaf(zv[2], wzA[4 * kq + 2], g2);
                    g3 = fmaf(zv[3], wzA[4 * kq + 3], g3);
                }
#pragma unroll
                for (int kq = 0; kq < 8; ++kq) {           // h part, chunk A
                    f32x4 hv = hR4[XA * 8 + kq];
                    g0 = fmaf(hv[0], whA[kq >> 2][(kq & 3) * 4 + 0], g0);
                    g1 = fmaf(hv[1], whA[kq >> 2][(kq & 3) * 4 + 1], g1);
                    g2 = fmaf(hv[2], whA[kq >> 2][(kq & 3) * 4 + 2], g2);
                    g3 = fmaf(hv[3], whA[kq >> 2][(kq & 3) * 4 + 3], g3);
                }
#pragma unroll
                for (int kq = 0; kq < 4; ++kq) {           // z part, chunk B
                    f32x4 zv = zb4[XB * 4 + kq];
                    G0 = fmaf(zv[0], wzB[4 * kq + 0], G0);
                    G1 = fmaf(zv[1], wzB[4 * kq + 1], G1);
                    G2 = fmaf(zv[2], wzB[4 * kq + 2], G2);
                    G3 = fmaf(zv[3], wzB[4 * kq + 3], G3);
                }
#pragma unroll
                for (int kq = 0; kq < 8; ++kq) {           // h part, chunk B
                    f32x4 hv = hR4[XB * 8 + kq];
                    G0 = fmaf(hv[0], whB[kq >> 2][(kq & 3) * 4 + 0], G0);
                    G1 = fmaf(hv[1], whB[kq >> 2][(kq & 3) * 4 + 1], G1);
                    G2 = fmaf(hv[2], whB[kq >> 2][(kq & 3) * 4 + 2], G2);
                    G3 = fmaf(hv[3], whB[kq >> 2][(kq & 3) * 4 + 3], G3);
                }
                float s = ((g0 + g1) + (g2 + g3)) + ((G0 + G1) + (G2 + G3));
                s += __shfl_xor(s, 1);                     // combine c5n
                float hn = tanh_fast(fmaf(y_t, wihy, ah) + s);
                if (c5n == 0) {
                    h_lds[nxt][o5] = hn;
                    hR[nxt][pH] = hn;
                    t_h[tt][o5] = hn;
                }
                if (tid == 0) t_y[tt] = y_t;
            }
            __syncthreads();                               // B5
        }

        flushb(t0);
        write_regs();
        __syncthreads();                                   // batch barrier
    }
}

// ---------------------------------------------------------------------------
// Post-pass: one block per timestep (unchanged).
// ---------------------------------------------------------------------------
__global__ __launch_bounds__(256) void k_post(
    const float* __restrict__ x, const float* __restrict__ yin_g,
    const float* __restrict__ Wpz, const float* __restrict__ Wpzm,
    const float* __restrict__ Wpzs,
    const float* __restrict__ Wpy, const float* __restrict__ ppr,
    const float* __restrict__ Wqy, const float* __restrict__ qpr,
    const float* __restrict__ Wd, const float* __restrict__ Wdm,
    const float* __restrict__ Wds,
    const float* __restrict__ Aq,
    const float* __restrict__ h_st, const float* __restrict__ z_st,
    const float* __restrict__ em_st, const float* __restrict__ es_st,
    const float* __restrict__ y_st,
    float* __restrict__ part)
{
    const float CC = -0.9189385332046727f;  // -0.5*log(2*pi)
    const int t = blockIdx.x;
    const int tid = threadIdx.x;
    __shared__ float xp[128], xdv[128], xcv[128], hp[128];
    __shared__ float zp[64], ztv[64], emv[64], esv[64];
    __shared__ float pzh[256], dhv[256];
    __shared__ float pmv[64], psv[64], dmv[128], dsv[128];
    __shared__ float rl[16];

    const int tp = t ? (t - 1) : (T - 1);
    if (tid < 128) {
        xp[tid]  = x[(size_t)tp * 128 + tid];
        xdv[tid] = t ? x[(size_t)(t - 1) * 128 + tid] : 0.f;
        xcv[tid] = x[(size_t)t * 128 + tid];
        hp[tid]  = t ? h_st[(size_t)(t - 1) * 128 + tid] : 0.f;
    } else {
        int m = tid - 128;
        if (m < 64) {
            zp[m]  = t ? z_st[(size_t)(t - 1) * 64 + m] : 0.f;
            ztv[m] = z_st[(size_t)t * 64 + m];
        } else {
            m -= 64;
            emv[m] = em_st[(size_t)t * 64 + m];
            esv[m] = es_st[(size_t)t * 64 + m];
        }
    }
    __syncthreads();

    const float y_t = y_st[t];
    const float y_prev = t ? y_st[t - 1] : 0.f;
    const float lf = (yin_g[t] != -1.0f) ? 1.f : 0.f;
    const int jj = tid;

    float ap = 0.f;
#pragma unroll 4
    for (int i = 0; i < 128; ++i) ap = fmaf(xp[i], Wpy[i * 256 + jj], ap);
    ap = fmaf(y_prev, Wpy[128 * 256 + jj], ap);
    float cp = fmaxf(ap, 0.f) * ppr[jj];

    float aqv = Aq[(size_t)t * 256 + jj];
#pragma unroll 4
    for (int i = 0; i < 128; ++i) aqv = fmaf(hp[i], Wqy[(128 + i) * 256 + jj], aqv);
    float cq = fmaxf(aqv, 0.f) * qpr[jj];

    float az = 0.f;
#pragma unroll 4
    for (int m = 0; m < 64; ++m) az = fmaf(zp[m], Wpz[m * 256 + jj], az);
    pzh[jj] = fmaxf(az, 0.f);

    float ad = 0.f;
#pragma unroll 4
    for (int i = 0; i < 128; ++i) ad = fmaf(xdv[i], Wd[i * 256 + jj], ad);
#pragma unroll 4
    for (int m = 0; m < 64; ++m) ad = fmaf(ztv[m], Wd[(128 + m) * 256 + jj], ad);
    ad = fmaf(y_t, Wd[192 * 256 + jj], ad);
    dhv[jj] = fmaxf(ad, 0.f);
    __syncthreads();

    {
        const int i_ = tid & 127;
        const float* W = (tid < 128) ? Wdm : Wds;
        float a = 0.f;
#pragma unroll 4
        for (int q2 = 0; q2 < 256; ++q2) a = fmaf(dhv[q2], W[q2 * 128 + i_], a);
        if (tid < 128) dmv[i_] = a; else dsv[i_] = softplusf_(a);
    }
    if (tid < 128) {
        const int m = tid & 63;
        const float* W = (tid < 64) ? Wpzm : Wpzs;
        float a = 0.f;
#pragma unroll 4
        for (int q2 = 0; q2 < 256; ++q2) a = fmaf(pzh[q2], W[q2 * 64 + m], a);
        if (tid < 64) pmv[m] = a; else psv[m] = softplusf_(a);
    }
    __syncthreads();

    float kldc = 0.f, recc = 0.f;
    if (tid < 64) {
        float es = esv[tid], em = emv[tid], pm = pmv[tid], ps = psv[tid];
        float d = em - pm;
        kldc = __logf(ps / es) + (es * es + d * d) / (2.f * ps * ps) - 0.5f;
    }
    if (tid < 128) {
        float dm = dmv[tid], ds = dsv[tid], xv = xcv[tid];
        float d = xv - dm;
        recc = CC + __logf(ds) + d * d / (2.f * ds * ds);
    }

#pragma unroll
    for (int d = 1; d < 64; d <<= 1) {
        cp += __shfl_xor(cp, d);
        cq += __shfl_xor(cq, d);
        kldc += __shfl_xor(kldc, d);
        recc += __shfl_xor(recc, d);
    }
    if ((tid & 63) == 0) {
        const int w = tid >> 6;
        rl[w * 4 + 0] = cp; rl[w * 4 + 1] = cq;
        rl[w * 4 + 2] = kldc; rl[w * 4 + 3] = recc;
    }
    __syncthreads();
    if (tid == 0) {
        float plog = rl[0] + rl[4] + rl[8]  + rl[12];
        float qlog = rl[1] + rl[5] + rl[9]  + rl[13];
        float kld  = rl[2] + rl[6] + rl[10] + rl[14];
        float rec  = rl[3] + rl[7] + rl[11] + rl[15];
        float p = sigmoidf_(plog), q = sigmoidf_(qlog);
        float bce  = -(y_t * __logf(p) + (1.f - y_t) * __logf(1.f - p));
        float addt = y_t * __logf(p * q) + (1.f - y_t) * __logf((1.f - p) * (1.f - q));
        float kcat = p * __logf(p / q) + (1.f - p) * __logf((1.f - p) / (1.f - q));
        float ul = 1.f - lf;
        float* pr = part + (size_t)t * 7;
        pr[0] = lf * kld;  pr[1] = lf * rec;  pr[2] = lf * bce;
        pr[3] = ul * kld;  pr[4] = ul * rec;  pr[5] = ul * kcat;
        pr[6] = lf * addt;
    }
}

__global__ __launch_bounds__(256) void k_final(const float* __restrict__ part,
                                               float* __restrict__ out)
{
    const int o = blockIdx.x;
    float s = 0.f;
    for (int b = threadIdx.x; b < T; b += 256) s += part[(size_t)b * 7 + o];
#pragma unroll
    for (int d = 1; d < 64; d <<= 1) s += __shfl_xor(s, d);
    __shared__ float l[4];
    if ((threadIdx.x & 63) == 0) l[threadIdx.x >> 6] = s;
    __syncthreads();
    if (threadIdx.x == 0) out[o] = (l[0] + l[1]) + (l[2] + l[3]);
}

extern "C" void kernel_launch(void* const* d_in, const int* in_sizes, int n_in,
                              void* d_out, int out_size, void* d_ws, size_t ws_size,
                              hipStream_t stream) {
    (void)in_sizes; (void)n_in; (void)out_size; (void)ws_size;
    const float* x    = (const float*)d_in[0];
    const float* yin  = (const float*)d_in[1];
    const float* ez   = (const float*)d_in[2];
    const float* eu   = (const float*)d_in[3];
    const float* Wpz  = (const float*)d_in[4];
    const float* Wpzm = (const float*)d_in[5];
    const float* Wpzs = (const float*)d_in[6];
    const float* Wpy  = (const float*)d_in[7];
    const float* ppr  = (const float*)d_in[8];
    const float* Wqy  = (const float*)d_in[9];
    const float* qpr  = (const float*)d_in[10];
    const float* Wenc = (const float*)d_in[11];
    const float* Wem  = (const float*)d_in[12];
    const float* Wes  = (const float*)d_in[13];
    const float* Wd   = (const float*)d_in[14];
    const float* Wdm  = (const float*)d_in[15];
    const float* Wds  = (const float*)d_in[16];
    const float* Wih  = (const float*)d_in[17];
    const float* Whh  = (const float*)d_in[18];

    float* ws = (float*)d_ws;
    float* Aq    = ws;                           // T*256
    float* Ae    = Aq    + (size_t)T * 256;      // T*256
    float* Ah    = Ae    + (size_t)T * 256;      // T*128
    float* h_st  = Ah    + (size_t)T * 128;      // T*128
    float* z_st  = h_st  + (size_t)T * 128;      // T*64
    float* em_st = z_st  + (size_t)T * 64;       // T*64
    float* es_st = em_st + (size_t)T * 64;       // T*64
    float* y_st  = es_st + (size_t)T * 64;       // T
    float* part  = y_st  + (size_t)T;            // T*7
    float* leu   = part  + (size_t)T * 7;        // T

    k_pre<<<T / 16, 256, 0, stream>>>(x, eu, Wqy, Wenc, Wih, Aq, Ae, Ah, leu);
    k_scan<<<1, 256, 0, stream>>>(Wqy, qpr, Wenc, Wem, Wes, Wih, Whh,
                                  yin, leu, ez, Aq, Ae, Ah,
                                  h_st, z_st, em_st, es_st, y_st);
    k_post<<<T, 256, 0, stream>>>(x, yin, Wpz, Wpzm, Wpzs, Wpy, ppr, Wqy, qpr,
                                  Wd, Wdm, Wds, Aq, h_st, z_st, em_st, es_st,
                                  y_st, part);
    k_final<<<7, 256, 0, stream>>>(part, (float*)d_out);
}

// Round 8
// 127700.610 us; speedup vs baseline: 1.8339x; 1.8339x over previous
//
#include <hip/hip_runtime.h>
#include <math.h>

#define T 16384

typedef float f32x4 __attribute__((ext_vector_type(4)));

__device__ __forceinline__ float softplusf_(float x) {
    return (x > 15.f) ? x : __logf(1.f + __expf(x));
}
__device__ __forceinline__ float sigmoidf_(float x) {
    return 1.f / (1.f + __expf(-x));
}
__device__ __forceinline__ float tanh_fast(float x) {
    float xc = fminf(fmaxf(x, -15.f), 15.f);
    float e = __expf(2.f * xc);
    return (e - 1.f) / (e + 1.f);
}

// 4 serial FMAs into one accumulator (one f32x4 of a 16-long chain)
#define FMAS(ACC, DV, WV) do{ \
  ACC = fmaf((DV)[0], (WV)[0], ACC); ACC = fmaf((DV)[1], (WV)[1], ACC); \
  ACC = fmaf((DV)[2], (WV)[2], ACC); ACC = fmaf((DV)[3], (WV)[3], ACC); }while(0)
// element e -> accumulator e (k%4 residue chains, r3 structure)
#define FMA4(A0, A1, A2, A3, DV, WV) do{ \
  A0 = fmaf((DV)[0], (WV)[0], A0); A1 = fmaf((DV)[1], (WV)[1], A1); \
  A2 = fmaf((DV)[2], (WV)[2], A2); A3 = fmaf((DV)[3], (WV)[3], A3); }while(0)

// ---------------------------------------------------------------------------
// Precompute x-dependent matvec parts + logit(eps_u) (fully parallel).
// ---------------------------------------------------------------------------
__global__ __launch_bounds__(256) void k_pre(
    const float* __restrict__ x, const float* __restrict__ eu_g,
    const float* __restrict__ Wqy, const float* __restrict__ Wenc,
    const float* __restrict__ Wih,
    float* __restrict__ Aq, float* __restrict__ Ae, float* __restrict__ Ah,
    float* __restrict__ leu_g)
{
    __shared__ float xs[16 * 128];
    const int t0 = blockIdx.x * 16;
    for (int r = threadIdx.x; r < 16 * 128; r += 256) xs[r] = x[t0 * 128 + r];
    __syncthreads();
    const int j = threadIdx.x;
    if (j < 16) {
        float eu = eu_g[t0 + j];
        leu_g[t0 + j] = __logf(eu) - __logf(1.f - eu);
    }
    for (int tt = 0; tt < 16; ++tt) {
        float aq = 0.f, ae = 0.f;
#pragma unroll 8
        for (int i = 0; i < 128; ++i) {
            float xv = xs[tt * 128 + i];
            aq = fmaf(xv, Wqy[i * 256 + j], aq);
            ae = fmaf(xv, Wenc[i * 256 + j], ae);
        }
        Aq[(size_t)(t0 + tt) * 256 + j] = aq;
        Ae[(size_t)(t0 + tt) * 256 + j] = ae;
    }
    if (j < 128) {
        for (int tt = 0; tt < 16; ++tt) {
            float ah = 0.f;
#pragma unroll 8
            for (int i = 0; i < 128; ++i)
                ah = fmaf(xs[tt * 128 + i], Wih[(65 + i) * 128 + j], ah);
            Ah[(size_t)(t0 + tt) * 128 + j] = ah;
        }
    }
}

// ---------------------------------------------------------------------------
// Sequential scan: 1 block x 1024 threads (16 waves, 4/SIMD, 128-VGPR sweet
// spot). Per-thread register weights <= 96 floats (no spill pressure):
//   all threads : W_enc h-chunk (32) -- thread (j, c) owns k === c (mod 4)
//   tid < 512   : W_enc_mean/std chunk (64) -- thread (m, sel, c4)
//   tid >= 512  : W_ih-z + W_hh chunk (48+1) -- thread (o, c5)
// W_q_y h-part (128 KB) in LDS, read only on unlabeled steps.
// Summation trees match r3 exactly; chain-internal rotations (bank spreading)
// follow r6 (empirically bf16-invisible).
// ---------------------------------------------------------------------------
__global__ __launch_bounds__(1024)
void k_scan(
    const float* __restrict__ Wqy, const float* __restrict__ qpr,
    const float* __restrict__ Wenc,
    const float* __restrict__ Wem0, const float* __restrict__ Wes0,
    const float* __restrict__ Wih, const float* __restrict__ Whh,
    const float* __restrict__ yin_g, const float* __restrict__ leu_g,
    const float* __restrict__ ez_g,
    const float* __restrict__ Aq, const float* __restrict__ Ae,
    const float* __restrict__ Ah,
    float* __restrict__ h_st, float* __restrict__ z_st,
    float* __restrict__ em_st, float* __restrict__ es_st,
    float* __restrict__ y_st)
{
    const int tid = threadIdx.x;
    const int j  = tid >> 2;          // S1/S3 output column (0..255)
    const int cc = tid & 3;           // S1/S3 K-residue class
    // S4 (tid<512): m (0..63), sel (0=mean,1=std), c4 = chunk of 64 over eh
    const int m   = (tid >> 3) & 63;
    const int sel = (tid >> 2) & 1;
    const int c4  = tid & 3;
    // S5 (tid>=512): o (0..127), c5 = chunk {16 z + 32 h}
    const int u5 = tid & 511;
    const int o  = u5 >> 2;
    const int c5 = u5 & 3;

    // ---- LDS (~139 KB) ----
    __shared__ __align__(16) f32x4 wqP[8][1024];   // 128 KB W_q_y h-part
    __shared__ __align__(16) float hL[2][128];     // h linear (S5 reads)
    __shared__ __align__(16) float hP[2][128];     // h permuted: pos=(o&3)*32+(o>>2)
    __shared__ __align__(16) float eh_lds[256];
    __shared__ __align__(16) float z_lds[64];
    __shared__ float red16[16];
    __shared__ __align__(16) float t_h[4][128];
    __shared__ __align__(16) float t_z[4][64];
    __shared__ __align__(16) float t_em[4][64];
    __shared__ __align__(16) float t_es[4][64];
    __shared__ float t_y[4];

    // ---- register weights (constant indices after unroll) ----
    // S3: weP4[idx] e-half (idx 0..3) / E-half (4..7), pre-rotated by g=(idx+cc)&3
    f32x4 weP4[8];
#pragma unroll
    for (int idx = 0; idx < 4; ++idx) {
        const int g = (idx + cc) & 3;
#pragma unroll
        for (int e = 0; e < 4; ++e) {
            weP4[idx][e]     = Wenc[(129 + cc + 16 * g + 4 * e) * 256 + j];
            weP4[4 + idx][e] = Wenc[(193 + cc + 16 * g + 4 * e) * 256 + j];
        }
    }
    const float wey = Wenc[128 * 256 + j];
    const float qpj = qpr[j];

    // S4 weights (tid<512 meaningful; loaded by all for uniform code)
    f32x4 wm4[16];
    {
        const float* Wm = sel ? Wes0 : Wem0;
#pragma unroll
        for (int idx = 0; idx < 16; ++idx) {
            const int kq = (idx + 2 * c4) & 15;
#pragma unroll
            for (int e = 0; e < 4; ++e)
                wm4[idx][e] = Wm[(c4 * 64 + 4 * kq + e) * 64 + m];
        }
    }
    // S5 weights
    f32x4 wz4[4], wh4[8];
#pragma unroll
    for (int idx = 0; idx < 4; ++idx) {
        const int kq = (idx + c5) & 3;
#pragma unroll
        for (int e = 0; e < 4; ++e)
            wz4[idx][e] = Wih[(1 + c5 * 16 + 4 * kq + e) * 128 + o];
    }
#pragma unroll
    for (int idx = 0; idx < 8; ++idx) {
        const int kq = (idx + 2 * c5) & 7;
#pragma unroll
        for (int e = 0; e < 4; ++e)
            wh4[idx][e] = Whh[(c5 * 32 + 4 * kq + e) * 128 + o];
    }
    const float wihy = Wih[o];

    // W_q_y h-part -> LDS [group g][tid] (lane-consecutive, conflict-free)
#pragma unroll
    for (int g = 0; g < 8; ++g) {
        f32x4 v;
#pragma unroll
        for (int e = 0; e < 4; ++e)
            v[e] = Wqy[(128 + cc + 16 * g + 4 * e) * 256 + j];
        wqP[g][tid] = v;
    }
    if (tid < 128) { hL[0][tid] = 0.f; hP[0][tid] = 0.f; }

    // per-step stream prefetch (1 step ahead)
    float aq_n = Aq[j];
    float ae_n = Ae[j];
    float yin_n = yin_g[0];
    float leu_n = leu_g[0];
    float ez_n = (tid < 512) ? ez_g[m] : 0.f;
    float ah_n = (tid >= 512) ? Ah[o] : 0.f;

    __syncthreads();

    for (int t0 = 0; t0 < T; t0 += 4) {
        for (int tt = 0; tt < 4; ++tt) {
            const int t = t0 + tt;
            const int cur = t & 1, nxt = cur ^ 1;
            const float aq = aq_n, ae = ae_n, yin = yin_n, leu = leu_n;
            const float ezv = ez_n, ahv = ah_n;
            const int tn = (t + 1 < T) ? t + 1 : t;
            aq_n = Aq[(size_t)tn * 256 + j];
            ae_n = Ae[(size_t)tn * 256 + j];
            yin_n = yin_g[tn];
            leu_n = leu_g[tn];
            if (tid < 512) ez_n = ez_g[(size_t)tn * 64 + m];
            else           ah_n = Ah[(size_t)tn * 128 + o];

            const f32x4* __restrict__ hPb = (const f32x4*)&hP[cur][cc * 32];

            float y_t, ehdot;
            if (yin == -1.0f) {
                // fused q-dot + eh-dot (shared hP reads)
                float a = 0.f, A = 0.f, e_ = 0.f, E_ = 0.f;
#pragma unroll
                for (int idx = 0; idx < 4; ++idx) {
                    const int g = (idx + cc) & 3;
                    f32x4 hv = hPb[g];
                    f32x4 wq = wqP[g][tid];
                    FMAS(a,  hv, wq);
                    FMAS(e_, hv, weP4[idx]);
                }
#pragma unroll
                for (int idx = 0; idx < 4; ++idx) {
                    const int g = (idx + cc) & 3;
                    f32x4 hv = hPb[4 + g];
                    f32x4 wq = wqP[4 + g][tid];
                    FMAS(A,  hv, wq);
                    FMAS(E_, hv, weP4[4 + idx]);
                }
                float sa = a;  sa += __shfl_xor(sa, 1); sa += __shfl_xor(sa, 2);
                float sA = A;  sA += __shfl_xor(sA, 1); sA += __shfl_xor(sA, 2);
                float se = e_; se += __shfl_xor(se, 1); se += __shfl_xor(se, 2);
                float sE = E_; sE += __shfl_xor(sE, 1); sE += __shfl_xor(sE, 2);
                const float sQ = sa + sA;
                ehdot = se + sE;
                float cqv = (cc == 0) ? fmaxf(aq + sQ, 0.f) * qpj : 0.f;
#pragma unroll
                for (int d = 1; d < 64; d <<= 1) cqv += __shfl_xor(cqv, d);
                if ((tid & 63) == 0) red16[tid >> 6] = cqv;
                __syncthreads();                                   // B1
                const float qA = (red16[0] + red16[1]) + (red16[2] + red16[3]);
                const float qB = (red16[4] + red16[5]) + (red16[6] + red16[7]);
                const float qC = (red16[8] + red16[9]) + (red16[10] + red16[11]);
                const float qD = (red16[12] + red16[13]) + (red16[14] + red16[15]);
                const float qlog = (qA + qB) + (qC + qD);
                y_t = sigmoidf_(leu + qlog);
            } else {
                float e_ = 0.f, E_ = 0.f;
#pragma unroll
                for (int idx = 0; idx < 4; ++idx) {
                    const int g = (idx + cc) & 3;
                    FMAS(e_, hPb[g],     weP4[idx]);
                    FMAS(E_, hPb[4 + g], weP4[4 + idx]);
                }
                float se = e_; se += __shfl_xor(se, 1); se += __shfl_xor(se, 2);
                float sE = E_; sE += __shfl_xor(sE, 1); sE += __shfl_xor(sE, 2);
                ehdot = se + sE;
                y_t = yin;
            }

            // S3 finalize: eh = relu(Ae + y*wey + h-dot)
            if (cc == 0)
                eh_lds[j] = fmaxf(fmaf(y_t, wey, ae) + ehdot, 0.f);
            __syncthreads();                                       // B3

            // S4 (tid<512): em/es over eh(256); z = ez*softplus(es)+em
            if (tid < 512) {
                const f32x4* __restrict__ eb4 = (const f32x4*)eh_lds;
                float b0 = 0.f, b1 = 0.f, b2 = 0.f, b3 = 0.f;
#pragma unroll
                for (int idx = 0; idx < 16; ++idx) {
                    const int kq = (idx + 2 * c4) & 15;
                    f32x4 ev = eb4[c4 * 16 + kq];
                    FMA4(b0, b1, b2, b3, ev, wm4[idx]);
                }
                float s = (b0 + b1) + (b2 + b3);
                s += __shfl_xor(s, 1);
                s += __shfl_xor(s, 2);
                const float other = __shfl_xor(s, 4);
                const float em_pre = sel ? other : s;
                const float es_pre = sel ? s : other;
                const float es = softplusf_(es_pre);
                const float zm = fmaf(ezv, es, em_pre);
                if ((tid & 7) == 0) {
                    z_lds[m] = zm;
                    t_z[tt][m] = zm; t_em[tt][m] = em_pre; t_es[tt][m] = es;
                }
            }
            __syncthreads();                                       // B4

            // S5 (tid>=512): h' = tanh(Ah + y*wihy + z@Wih_z + h@W_hh)
            if (tid >= 512) {
                const f32x4* __restrict__ zb4 = (const f32x4*)z_lds;
                const f32x4* __restrict__ hb4 = (const f32x4*)&hL[cur][0];
                float g0 = 0.f, g1 = 0.f, g2 = 0.f, g3 = 0.f;
#pragma unroll
                for (int idx = 0; idx < 4; ++idx) {
                    const int kq = (idx + c5) & 3;
                    f32x4 zv = zb4[c5 * 4 + kq];
                    FMA4(g0, g1, g2, g3, zv, wz4[idx]);
                }
#pragma unroll
                for (int idx = 0; idx < 8; ++idx) {
                    const int kq = (idx + 2 * c5) & 7;
                    f32x4 hv = hb4[c5 * 8 + kq];
                    FMA4(g0, g1, g2, g3, hv, wh4[idx]);
                }
                float s = (g0 + g1) + (g2 + g3);
                s += __shfl_xor(s, 1);
                s += __shfl_xor(s, 2);
                const float hn = tanh_fast(fmaf(y_t, wihy, ahv) + s);
                if (c5 == 0) {
                    hL[nxt][o] = hn;
                    hP[nxt][(o & 3) * 32 + (o >> 2)] = hn;
                    t_h[tt][o] = hn;
                }
            }
            if (tid == 0) t_y[tt] = y_t;
            __syncthreads();                                       // B5
        }

        // batched trajectory flush (stores drain at next step's barrier)
        if (tid < 64)
            ((f32x4*)(es_st + (size_t)t0 * 64))[tid] = ((const f32x4*)&t_es[0][0])[tid];
        if (tid < 128) {
            ((f32x4*)(h_st + (size_t)t0 * 128))[tid] = ((const f32x4*)&t_h[0][0])[tid];
        } else if (tid < 192) {
            ((f32x4*)(z_st + (size_t)t0 * 64))[tid - 128] = ((const f32x4*)&t_z[0][0])[tid - 128];
        } else if (tid < 256) {
            ((f32x4*)(em_st + (size_t)t0 * 64))[tid - 192] = ((const f32x4*)&t_em[0][0])[tid - 192];
        } else if (tid >= 252 + 8 && tid < 264) {
            // (unused range placeholder, kept simple below)
        }
        if (tid >= 508 && tid < 512) y_st[t0 + (tid - 508)] = t_y[tid - 508];
    }
}

// ---------------------------------------------------------------------------
// Post-pass: one block per timestep (unchanged).
// ---------------------------------------------------------------------------
__global__ __launch_bounds__(256) void k_post(
    const float* __restrict__ x, const float* __restrict__ yin_g,
    const float* __restrict__ Wpz, const float* __restrict__ Wpzm,
    const float* __restrict__ Wpzs,
    const float* __restrict__ Wpy, const float* __restrict__ ppr,
    const float* __restrict__ Wqy, const float* __restrict__ qpr,
    const float* __restrict__ Wd, const float* __restrict__ Wdm,
    const float* __restrict__ Wds,
    const float* __restrict__ Aq,
    const float* __restrict__ h_st, const float* __restrict__ z_st,
    const float* __restrict__ em_st, const float* __restrict__ es_st,
    const float* __restrict__ y_st,
    float* __restrict__ part)
{
    const float CC = -0.9189385332046727f;  // -0.5*log(2*pi)
    const int t = blockIdx.x;
    const int tid = threadIdx.x;
    __shared__ float xp[128], xdv[128], xcv[128], hp[128];
    __shared__ float zp[64], ztv[64], emv[64], esv[64];
    __shared__ float pzh[256], dhv[256];
    __shared__ float pmv[64], psv[64], dmv[128], dsv[128];
    __shared__ float rl[16];

    const int tp = t ? (t - 1) : (T - 1);
    if (tid < 128) {
        xp[tid]  = x[(size_t)tp * 128 + tid];
        xdv[tid] = t ? x[(size_t)(t - 1) * 128 + tid] : 0.f;
        xcv[tid] = x[(size_t)t * 128 + tid];
        hp[tid]  = t ? h_st[(size_t)(t - 1) * 128 + tid] : 0.f;
    } else {
        int mm = tid - 128;
        if (mm < 64) {
            zp[mm]  = t ? z_st[(size_t)(t - 1) * 64 + mm] : 0.f;
            ztv[mm] = z_st[(size_t)t * 64 + mm];
        } else {
            mm -= 64;
            emv[mm] = em_st[(size_t)t * 64 + mm];
            esv[mm] = es_st[(size_t)t * 64 + mm];
        }
    }
    __syncthreads();

    const float y_t = y_st[t];
    const float y_prev = t ? y_st[t - 1] : 0.f;
    const float lf = (yin_g[t] != -1.0f) ? 1.f : 0.f;
    const int jj = tid;

    float ap = 0.f;
#pragma unroll 4
    for (int i = 0; i < 128; ++i) ap = fmaf(xp[i], Wpy[i * 256 + jj], ap);
    ap = fmaf(y_prev, Wpy[128 * 256 + jj], ap);
    float cp = fmaxf(ap, 0.f) * ppr[jj];

    float aqv = Aq[(size_t)t * 256 + jj];
#pragma unroll 4
    for (int i = 0; i < 128; ++i) aqv = fmaf(hp[i], Wqy[(128 + i) * 256 + jj], aqv);
    float cq = fmaxf(aqv, 0.f) * qpr[jj];

    float az = 0.f;
#pragma unroll 4
    for (int mm = 0; mm < 64; ++mm) az = fmaf(zp[mm], Wpz[mm * 256 + jj], az);
    pzh[jj] = fmaxf(az, 0.f);

    float ad = 0.f;
#pragma unroll 4
    for (int i = 0; i < 128; ++i) ad = fmaf(xdv[i], Wd[i * 256 + jj], ad);
#pragma unroll 4
    for (int mm = 0; mm < 64; ++mm) ad = fmaf(ztv[mm], Wd[(128 + mm) * 256 + jj], ad);
    ad = fmaf(y_t, Wd[192 * 256 + jj], ad);
    dhv[jj] = fmaxf(ad, 0.f);
    __syncthreads();

    {
        const int i_ = tid & 127;
        const float* W = (tid < 128) ? Wdm : Wds;
        float a = 0.f;
#pragma unroll 4
        for (int q2 = 0; q2 < 256; ++q2) a = fmaf(dhv[q2], W[q2 * 128 + i_], a);
        if (tid < 128) dmv[i_] = a; else dsv[i_] = softplusf_(a);
    }
    if (tid < 128) {
        const int mm = tid & 63;
        const float* W = (tid < 64) ? Wpzm : Wpzs;
        float a = 0.f;
#pragma unroll 4
        for (int q2 = 0; q2 < 256; ++q2) a = fmaf(pzh[q2], W[q2 * 64 + mm], a);
        if (tid < 64) pmv[mm] = a; else psv[mm] = softplusf_(a);
    }
    __syncthreads();

    float kldc = 0.f, recc = 0.f;
    if (tid < 64) {
        float es = esv[tid], em = emv[tid], pm = pmv[tid], ps = psv[tid];
        float d = em - pm;
        kldc = __logf(ps / es) + (es * es + d * d) / (2.f * ps * ps) - 0.5f;
    }
    if (tid < 128) {
        float dm = dmv[tid], ds = dsv[tid], xv = xcv[tid];
        float d = xv - dm;
        recc = CC + __logf(ds) + d * d / (2.f * ds * ds);
    }

#pragma unroll
    for (int d = 1; d < 64; d <<= 1) {
        cp += __shfl_xor(cp, d);
        cq += __shfl_xor(cq, d);
        kldc += __shfl_xor(kldc, d);
        recc += __shfl_xor(recc, d);
    }
    if ((tid & 63) == 0) {
        const int w = tid >> 6;
        rl[w * 4 + 0] = cp; rl[w * 4 + 1] = cq;
        rl[w * 4 + 2] = kldc; rl[w * 4 + 3] = recc;
    }
    __syncthreads();
    if (tid == 0) {
        float plog = rl[0] + rl[4] + rl[8]  + rl[12];
        float qlog = rl[1] + rl[5] + rl[9]  + rl[13];
        float kld  = rl[2] + rl[6] + rl[10] + rl[14];
        float rec  = rl[3] + rl[7] + rl[11] + rl[15];
        float p = sigmoidf_(plog), q = sigmoidf_(qlog);
        float bce  = -(y_t * __logf(p) + (1.f - y_t) * __logf(1.f - p));
        float addt = y_t * __logf(p * q) + (1.f - y_t) * __logf((1.f - p) * (1.f - q));
        float kcat = p * __logf(p / q) + (1.f - p) * __logf((1.f - p) / (1.f - q));
        float ul = 1.f - lf;
        float* pr = part + (size_t)t * 7;
        pr[0] = lf * kld;  pr[1] = lf * rec;  pr[2] = lf * bce;
        pr[3] = ul * kld;  pr[4] = ul * rec;  pr[5] = ul * kcat;
        pr[6] = lf * addt;
    }
}

__global__ __launch_bounds__(256) void k_final(const float* __restrict__ part,
                                               float* __restrict__ out)
{
    const int oo = blockIdx.x;
    float s = 0.f;
    for (int b = threadIdx.x; b < T; b += 256) s += part[(size_t)b * 7 + oo];
#pragma unroll
    for (int d = 1; d < 64; d <<= 1) s += __shfl_xor(s, d);
    __shared__ float l[4];
    if ((threadIdx.x & 63) == 0) l[threadIdx.x >> 6] = s;
    __syncthreads();
    if (threadIdx.x == 0) out[oo] = (l[0] + l[1]) + (l[2] + l[3]);
}

extern "C" void kernel_launch(void* const* d_in, const int* in_sizes, int n_in,
                              void* d_out, int out_size, void* d_ws, size_t ws_size,
                              hipStream_t stream) {
    (void)in_sizes; (void)n_in; (void)out_size; (void)ws_size;
    const float* x    = (const float*)d_in[0];
    const float* yin  = (const float*)d_in[1];
    const float* ez   = (const float*)d_in[2];
    const float* eu   = (const float*)d_in[3];
    const float* Wpz  = (const float*)d_in[4];
    const float* Wpzm = (const float*)d_in[5];
    const float* Wpzs = (const float*)d_in[6];
    const float* Wpy  = (const float*)d_in[7];
    const float* ppr  = (const float*)d_in[8];
    const float* Wqy  = (const float*)d_in[9];
    const float* qpr  = (const float*)d_in[10];
    const float* Wenc = (const float*)d_in[11];
    const float* Wem  = (const float*)d_in[12];
    const float* Wes  = (const float*)d_in[13];
    const float* Wd   = (const float*)d_in[14];
    const float* Wdm  = (const float*)d_in[15];
    const float* Wds  = (const float*)d_in[16];
    const float* Wih  = (const float*)d_in[17];
    const float* Whh  = (const float*)d_in[18];

    float* ws = (float*)d_ws;
    float* Aq    = ws;                           // T*256
    float* Ae    = Aq    + (size_t)T * 256;      // T*256
    float* Ah    = Ae    + (size_t)T * 256;      // T*128
    float* h_st  = Ah    + (size_t)T * 128;      // T*128
    float* z_st  = h_st  + (size_t)T * 128;      // T*64
    float* em_st = z_st  + (size_t)T * 64;       // T*64
    float* es_st = em_st + (size_t)T * 64;       // T*64
    float* y_st  = es_st + (size_t)T * 64;       // T
    float* part  = y_st  + (size_t)T;            // T*7
    float* leu   = part  + (size_t)T * 7;        // T

    k_pre<<<T / 16, 256, 0, stream>>>(x, eu, Wqy, Wenc, Wih, Aq, Ae, Ah, leu);
    k_scan<<<1, 1024, 0, stream>>>(Wqy, qpr, Wenc, Wem, Wes, Wih, Whh,
                                   yin, leu, ez, Aq, Ae, Ah,
                                   h_st, z_st, em_st, es_st, y_st);
    k_post<<<T, 256, 0, stream>>>(x, yin, Wpz, Wpzm, Wpzs, Wpy, ppr, Wqy, qpr,
                                  Wd, Wdm, Wds, Aq, h_st, z_st, em_st, es_st,
                                  y_st, part);
    k_final<<<7, 256, 0, stream>>>(part, (float*)d_out);
}

// Round 9
// 80021.643 us; speedup vs baseline: 2.9266x; 1.5958x over previous
//
#include <hip/hip_runtime.h>
#include <math.h>

#define T 16384

typedef float f32x4 __attribute__((ext_vector_type(4)));

__device__ __forceinline__ float softplusf_(float x) {
    return (x > 15.f) ? x : __logf(1.f + __expf(x));
}
__device__ __forceinline__ float sigmoidf_(float x) {
    return 1.f / (1.f + __expf(-x));
}
__device__ __forceinline__ float tanh_fast(float x) {
    float xc = fminf(fmaxf(x, -15.f), 15.f);
    float e = __expf(2.f * xc);
    return (e - 1.f) / (e + 1.f);
}

// element e -> accumulator e (k%4 residue chains; same product order as r3's
// D16 / r8's FMA4 — both verified bit-exact, absmax 0.0)
#define FMA4(A0, A1, A2, A3, DV, WV) do{ \
  A0 = fmaf((DV)[0], (WV)[0], A0); A1 = fmaf((DV)[1], (WV)[1], A1); \
  A2 = fmaf((DV)[2], (WV)[2], A2); A3 = fmaf((DV)[3], (WV)[3], A3); }while(0)

// ---------------------------------------------------------------------------
// Precompute x-dependent matvec parts + logit(eps_u) + W_q_y h-part transpose
// (WqT[g][tid] f32x4, lane-coalesced for the scan's per-step L2 re-read).
// ---------------------------------------------------------------------------
__global__ __launch_bounds__(256) void k_pre(
    const float* __restrict__ x, const float* __restrict__ eu_g,
    const float* __restrict__ Wqy, const float* __restrict__ Wenc,
    const float* __restrict__ Wih,
    float* __restrict__ Aq, float* __restrict__ Ae, float* __restrict__ Ah,
    float* __restrict__ leu_g, float* __restrict__ WqT)
{
    __shared__ float xs[16 * 128];
    const int t0 = blockIdx.x * 16;
    for (int r = threadIdx.x; r < 16 * 128; r += 256) xs[r] = x[t0 * 128 + r];
    __syncthreads();
    const int j = threadIdx.x;
    if (j < 16) {
        float eu = eu_g[t0 + j];
        leu_g[t0 + j] = __logf(eu) - __logf(1.f - eu);
    }
    if (blockIdx.x == 0) {
        // transpose W_q_y h-part into per-scan-thread contiguous f32x4 groups
        for (int tid2 = threadIdx.x; tid2 < 512; tid2 += 256) {
            const int jj2 = tid2 >> 1, c1b = tid2 & 1;
            for (int g = 0; g < 16; ++g) {
                f32x4 v;
#pragma unroll
                for (int e = 0; e < 4; ++e)
                    v[e] = Wqy[(128 + c1b * 64 + 4 * g + e) * 256 + jj2];
                ((f32x4*)WqT)[g * 512 + tid2] = v;
            }
        }
    }
    for (int tt = 0; tt < 16; ++tt) {
        float aq = 0.f, ae = 0.f;
#pragma unroll 8
        for (int i = 0; i < 128; ++i) {
            float xv = xs[tt * 128 + i];
            aq = fmaf(xv, Wqy[i * 256 + j], aq);
            ae = fmaf(xv, Wenc[i * 256 + j], ae);
        }
        Aq[(size_t)(t0 + tt) * 256 + j] = aq;
        Ae[(size_t)(t0 + tt) * 256 + j] = ae;
    }
    if (j < 128) {
        for (int tt = 0; tt < 16; ++tt) {
            float ah = 0.f;
#pragma unroll 8
            for (int i = 0; i < 128; ++i)
                ah = fmaf(xs[tt * 128 + i], Wih[(65 + i) * 128 + j], ah);
            Ah[(size_t)(t0 + tt) * 128 + j] = ah;
        }
    }
}

// ---------------------------------------------------------------------------
// Sequential scan: 1 block x 512 threads.
// Residency plan (allocator-proof for the big matrices):
//   - W_enc-h   : thread-private LDS weL[16][512] (128 KB, own-slot reads,
//                 conflict-free ds_read_b128, no barriers needed)
//   - W_q_y-h   : L2 via WqT, re-read only on unlabeled steps (~50%)
//   - Wem/Wes   : registers wm4[16] (64 f)   } 112 f/thread requested;
//   - Whh,Wih-z : registers wh4[8],wz4[4]    } worst case = L2 remat (= r3)
// Chain structures copied verbatim from r3 (S1/S3) and r8 (S4/S5) — both
// passed with absmax 0.0.
// ---------------------------------------------------------------------------
__global__ __launch_bounds__(512)
__attribute__((amdgpu_waves_per_eu(2, 2)))
void k_scan(
    const float* __restrict__ qpr, const float* __restrict__ Wenc,
    const float* __restrict__ Wem0, const float* __restrict__ Wes0,
    const float* __restrict__ Wih, const float* __restrict__ Whh,
    const float* __restrict__ yin_g, const float* __restrict__ leu_g,
    const float* __restrict__ ez_g,
    const float* __restrict__ Aq, const float* __restrict__ Ae,
    const float* __restrict__ Ah, const float* __restrict__ WqT,
    float* __restrict__ h_st, float* __restrict__ z_st,
    float* __restrict__ em_st, float* __restrict__ es_st,
    float* __restrict__ y_st)
{
    const int tid = threadIdx.x;
    const int j  = tid >> 1, c1 = tid & 1;               // S1/S3 (r3 mapping)
    const int m   = (tid >> 3) & 63;                     // S4 (r8 mapping)
    const int sel = (tid >> 2) & 1;
    const int c4  = tid & 3;
    const int o  = tid >> 2, c5 = tid & 3;               // S5 (r8 mapping)

    // ---- LDS (~138.5 KB) ----
    __shared__ __align__(16) f32x4 weL[16][512];         // 128 KB W_enc-h
    __shared__ __align__(16) float h_lds[2][128];
    __shared__ __align__(16) float eh_lds[256];
    __shared__ __align__(16) float z_lds[64];
    __shared__ float red[8];
    __shared__ __align__(16) float t_h[4][128];
    __shared__ __align__(16) float t_z[4][64];
    __shared__ __align__(16) float t_em[4][64];
    __shared__ __align__(16) float t_es[4][64];
    __shared__ float t_y[4];

    // ---- register weights (constant indices; r8's pre-rotated layouts) ----
    f32x4 wm4[16];
    {
        const float* Wm = sel ? Wes0 : Wem0;
#pragma unroll
        for (int idx = 0; idx < 16; ++idx) {
            const int kq = (idx + 2 * c4) & 15;
#pragma unroll
            for (int e = 0; e < 4; ++e)
                wm4[idx][e] = Wm[(c4 * 64 + 4 * kq + e) * 64 + m];
        }
    }
    f32x4 wz4[4], wh4[8];
#pragma unroll
    for (int idx = 0; idx < 4; ++idx) {
        const int kq = (idx + c5) & 3;
#pragma unroll
        for (int e = 0; e < 4; ++e)
            wz4[idx][e] = Wih[(1 + c5 * 16 + 4 * kq + e) * 128 + o];
    }
#pragma unroll
    for (int idx = 0; idx < 8; ++idx) {
        const int kq = (idx + 2 * c5) & 7;
#pragma unroll
        for (int e = 0; e < 4; ++e)
            wh4[idx][e] = Whh[(c5 * 32 + 4 * kq + e) * 128 + o];
    }
    const float wey  = Wenc[128 * 256 + j];
    const float qpj  = qpr[j];
    const float wihy = Wih[o];

    // ---- W_enc-h -> thread-private LDS (own slot; no cross-thread reads) ----
#pragma unroll 4
    for (int g = 0; g < 16; ++g) {
        f32x4 v;
#pragma unroll
        for (int e = 0; e < 4; ++e)
            v[e] = Wenc[(129 + c1 * 64 + 4 * g + e) * 256 + j];
        weL[g][tid] = v;
    }
    if (tid < 128) h_lds[0][tid] = 0.f;

    // ---- per-step stream prefetch (1 step ahead, registers) ----
    float aq_n = Aq[j];
    float ae_n = Ae[j];
    float yin_n = yin_g[0];
    float leu_n = leu_g[0];
    float ez_n = ez_g[m];
    float ah_n = Ah[o];

    const f32x4* __restrict__ Wq4 = (const f32x4*)WqT;
    __syncthreads();

    for (int t0 = 0; t0 < T; t0 += 4) {
        for (int tt = 0; tt < 4; ++tt) {
            const int t = t0 + tt;
            const int cur = t & 1, nxt = cur ^ 1;
            const float aq = aq_n, ae = ae_n, yin = yin_n, leu = leu_n;
            const float ezv = ez_n, ahv = ah_n;
            const int tn = (t + 1 < T) ? t + 1 : t;
            aq_n = Aq[(size_t)tn * 256 + j];
            ae_n = Ae[(size_t)tn * 256 + j];
            yin_n = yin_g[tn];
            leu_n = leu_g[tn];
            ez_n = ez_g[(size_t)tn * 64 + m];
            ah_n = Ah[(size_t)tn * 128 + o];

            const f32x4* __restrict__ hb4 = (const f32x4*)&h_lds[cur][c1 * 64];

            float y_t, ehdot;
            if (yin == -1.0f) {
                // fused q-dot (L2 weights) + eh-dot (LDS weights), shared h
                float a0 = 0.f, a1 = 0.f, a2 = 0.f, a3 = 0.f;
                float e0 = 0.f, e1 = 0.f, e2 = 0.f, e3 = 0.f;
#pragma unroll
                for (int g = 0; g < 16; ++g) {
                    f32x4 hv = hb4[g];
                    f32x4 qv = Wq4[g * 512 + tid];
                    f32x4 ev = weL[g][tid];
                    FMA4(a0, a1, a2, a3, hv, qv);
                    FMA4(e0, e1, e2, e3, hv, ev);
                }
                float s = (a0 + a1) + (a2 + a3);
                ehdot   = (e0 + e1) + (e2 + e3);
                s += __shfl_xor(s, 1);
                ehdot += __shfl_xor(ehdot, 1);
                float qh = fmaxf(aq + s, 0.f);
                float cq = (c1 == 0) ? qh * qpj : 0.f;
#pragma unroll
                for (int d = 1; d < 64; d <<= 1) cq += __shfl_xor(cq, d);
                if ((tid & 63) == 0) red[tid >> 6] = cq;
                __syncthreads();                           // B1
                float qlog = ((red[0] + red[1]) + (red[2] + red[3])) +
                             ((red[4] + red[5]) + (red[6] + red[7]));
                y_t = sigmoidf_(leu + qlog);
            } else {
                float e0 = 0.f, e1 = 0.f, e2 = 0.f, e3 = 0.f;
#pragma unroll
                for (int g = 0; g < 16; ++g) {
                    f32x4 hv = hb4[g];
                    f32x4 ev = weL[g][tid];
                    FMA4(e0, e1, e2, e3, hv, ev);
                }
                ehdot = (e0 + e1) + (e2 + e3);
                ehdot += __shfl_xor(ehdot, 1);
                y_t = yin;
            }

            // S3 finalize: eh = relu(Ae + y*wey + h-dot)
            if (c1 == 0)
                eh_lds[j] = fmaxf(fmaf(y_t, wey, ae) + ehdot, 0.f);
            __syncthreads();                               // B3

            // S4: em/es over eh(256); z = ez*softplus(es)+em  (r8 verbatim)
            {
                const f32x4* __restrict__ eb4 = (const f32x4*)eh_lds;
                float b0 = 0.f, b1 = 0.f, b2 = 0.f, b3 = 0.f;
#pragma unroll
                for (int idx = 0; idx < 16; ++idx) {
                    const int kq = (idx + 2 * c4) & 15;
                    f32x4 ev = eb4[c4 * 16 + kq];
                    FMA4(b0, b1, b2, b3, ev, wm4[idx]);
                }
                float s = (b0 + b1) + (b2 + b3);
                s += __shfl_xor(s, 1);
                s += __shfl_xor(s, 2);
                const float other = __shfl_xor(s, 4);
                const float em_pre = sel ? other : s;
                const float es_pre = sel ? s : other;
                const float es = softplusf_(es_pre);
                const float zm = fmaf(ezv, es, em_pre);
                if ((tid & 7) == 0) {
                    z_lds[m] = zm;
                    t_z[tt][m] = zm; t_em[tt][m] = em_pre; t_es[tt][m] = es;
                }
            }
            __syncthreads();                               // B4

            // S5: h' = tanh(Ah + y*wihy + z@Wih_z + h@W_hh)  (r8 verbatim)
            {
                const f32x4* __restrict__ zb4 = (const f32x4*)z_lds;
                const f32x4* __restrict__ hb5 = (const f32x4*)&h_lds[cur][0];
                float g0 = 0.f, g1 = 0.f, g2 = 0.f, g3 = 0.f;
#pragma unroll
                for (int idx = 0; idx < 4; ++idx) {
                    const int kq = (idx + c5) & 3;
                    f32x4 zv = zb4[c5 * 4 + kq];
                    FMA4(g0, g1, g2, g3, zv, wz4[idx]);
                }
#pragma unroll
                for (int idx = 0; idx < 8; ++idx) {
                    const int kq = (idx + 2 * c5) & 7;
                    f32x4 hv = hb5[c5 * 8 + kq];
                    FMA4(g0, g1, g2, g3, hv, wh4[idx]);
                }
                float s = (g0 + g1) + (g2 + g3);
                s += __shfl_xor(s, 1);
                s += __shfl_xor(s, 2);
                const float hn = tanh_fast(fmaf(y_t, wihy, ahv) + s);
                if (c5 == 0) {
                    h_lds[nxt][o] = hn;
                    t_h[tt][o] = hn;
                }
                if (tid == 0) t_y[tt] = y_t;
            }
            __syncthreads();                               // B5
        }

        // batched trajectory flush (fire-and-forget; drains at next barrier)
        if (tid < 128) {
            ((f32x4*)(h_st + (size_t)t0 * 128))[tid] = ((const f32x4*)&t_h[0][0])[tid];
        } else if (tid < 192) {
            ((f32x4*)(z_st + (size_t)t0 * 64))[tid - 128] = ((const f32x4*)&t_z[0][0])[tid - 128];
        } else if (tid < 256) {
            ((f32x4*)(em_st + (size_t)t0 * 64))[tid - 192] = ((const f32x4*)&t_em[0][0])[tid - 192];
        } else if (tid < 320) {
            ((f32x4*)(es_st + (size_t)t0 * 64))[tid - 256] = ((const f32x4*)&t_es[0][0])[tid - 256];
        } else if (tid < 324) {
            y_st[t0 + (tid - 320)] = t_y[tid - 320];
        }
    }
}

// ---------------------------------------------------------------------------
// Post-pass: one block per timestep (unchanged).
// ---------------------------------------------------------------------------
__global__ __launch_bounds__(256) void k_post(
    const float* __restrict__ x, const float* __restrict__ yin_g,
    const float* __restrict__ Wpz, const float* __restrict__ Wpzm,
    const float* __restrict__ Wpzs,
    const float* __restrict__ Wpy, const float* __restrict__ ppr,
    const float* __restrict__ Wqy, const float* __restrict__ qpr,
    const float* __restrict__ Wd, const float* __restrict__ Wdm,
    const float* __restrict__ Wds,
    const float* __restrict__ Aq,
    const float* __restrict__ h_st, const float* __restrict__ z_st,
    const float* __restrict__ em_st, const float* __restrict__ es_st,
    const float* __restrict__ y_st,
    float* __restrict__ part)
{
    const float CC = -0.9189385332046727f;  // -0.5*log(2*pi)
    const int t = blockIdx.x;
    const int tid = threadIdx.x;
    __shared__ float xp[128], xdv[128], xcv[128], hp[128];
    __shared__ float zp[64], ztv[64], emv[64], esv[64];
    __shared__ float pzh[256], dhv[256];
    __shared__ float pmv[64], psv[64], dmv[128], dsv[128];
    __shared__ float rl[16];

    const int tp = t ? (t - 1) : (T - 1);
    if (tid < 128) {
        xp[tid]  = x[(size_t)tp * 128 + tid];
        xdv[tid] = t ? x[(size_t)(t - 1) * 128 + tid] : 0.f;
        xcv[tid] = x[(size_t)t * 128 + tid];
        hp[tid]  = t ? h_st[(size_t)(t - 1) * 128 + tid] : 0.f;
    } else {
        int mm = tid - 128;
        if (mm < 64) {
            zp[mm]  = t ? z_st[(size_t)(t - 1) * 64 + mm] : 0.f;
            ztv[mm] = z_st[(size_t)t * 64 + mm];
        } else {
            mm -= 64;
            emv[mm] = em_st[(size_t)t * 64 + mm];
            esv[mm] = es_st[(size_t)t * 64 + mm];
        }
    }
    __syncthreads();

    const float y_t = y_st[t];
    const float y_prev = t ? y_st[t - 1] : 0.f;
    const float lf = (yin_g[t] != -1.0f) ? 1.f : 0.f;
    const int jj = tid;

    float ap = 0.f;
#pragma unroll 4
    for (int i = 0; i < 128; ++i) ap = fmaf(xp[i], Wpy[i * 256 + jj], ap);
    ap = fmaf(y_prev, Wpy[128 * 256 + jj], ap);
    float cp = fmaxf(ap, 0.f) * ppr[jj];

    float aqv = Aq[(size_t)t * 256 + jj];
#pragma unroll 4
    for (int i = 0; i < 128; ++i) aqv = fmaf(hp[i], Wqy[(128 + i) * 256 + jj], aqv);
    float cq = fmaxf(aqv, 0.f) * qpr[jj];

    float az = 0.f;
#pragma unroll 4
    for (int mm = 0; mm < 64; ++mm) az = fmaf(zp[mm], Wpz[mm * 256 + jj], az);
    pzh[jj] = fmaxf(az, 0.f);

    float ad = 0.f;
#pragma unroll 4
    for (int i = 0; i < 128; ++i) ad = fmaf(xdv[i], Wd[i * 256 + jj], ad);
#pragma unroll 4
    for (int mm = 0; mm < 64; ++mm) ad = fmaf(ztv[mm], Wd[(128 + mm) * 256 + jj], ad);
    ad = fmaf(y_t, Wd[192 * 256 + jj], ad);
    dhv[jj] = fmaxf(ad, 0.f);
    __syncthreads();

    {
        const int i_ = tid & 127;
        const float* W = (tid < 128) ? Wdm : Wds;
        float a = 0.f;
#pragma unroll 4
        for (int q2 = 0; q2 < 256; ++q2) a = fmaf(dhv[q2], W[q2 * 128 + i_], a);
        if (tid < 128) dmv[i_] = a; else dsv[i_] = softplusf_(a);
    }
    if (tid < 128) {
        const int mm = tid & 63;
        const float* W = (tid < 64) ? Wpzm : Wpzs;
        float a = 0.f;
#pragma unroll 4
        for (int q2 = 0; q2 < 256; ++q2) a = fmaf(pzh[q2], W[q2 * 64 + mm], a);
        if (tid < 64) pmv[mm] = a; else psv[mm] = softplusf_(a);
    }
    __syncthreads();

    float kldc = 0.f, recc = 0.f;
    if (tid < 64) {
        float es = esv[tid], em = emv[tid], pm = pmv[tid], ps = psv[tid];
        float d = em - pm;
        kldc = __logf(ps / es) + (es * es + d * d) / (2.f * ps * ps) - 0.5f;
    }
    if (tid < 128) {
        float dm = dmv[tid], ds = dsv[tid], xv = xcv[tid];
        float d = xv - dm;
        recc = CC + __logf(ds) + d * d / (2.f * ds * ds);
    }

#pragma unroll
    for (int d = 1; d < 64; d <<= 1) {
        cp += __shfl_xor(cp, d);
        cq += __shfl_xor(cq, d);
        kldc += __shfl_xor(kldc, d);
        recc += __shfl_xor(recc, d);
    }
    if ((tid & 63) == 0) {
        const int w = tid >> 6;
        rl[w * 4 + 0] = cp; rl[w * 4 + 1] = cq;
        rl[w * 4 + 2] = kldc; rl[w * 4 + 3] = recc;
    }
    __syncthreads();
    if (tid == 0) {
        float plog = rl[0] + rl[4] + rl[8]  + rl[12];
        float qlog = rl[1] + rl[5] + rl[9]  + rl[13];
        float kld  = rl[2] + rl[6] + rl[10] + rl[14];
        float rec  = rl[3] + rl[7] + rl[11] + rl[15];
        float p = sigmoidf_(plog), q = sigmoidf_(qlog);
        float bce  = -(y_t * __logf(p) + (1.f - y_t) * __logf(1.f - p));
        float addt = y_t * __logf(p * q) + (1.f - y_t) * __logf((1.f - p) * (1.f - q));
        float kcat = p * __logf(p / q) + (1.f - p) * __logf((1.f - p) / (1.f - q));
        float ul = 1.f - lf;
        float* pr = part + (size_t)t * 7;
        pr[0] = lf * kld;  pr[1] = lf * rec;  pr[2] = lf * bce;
        pr[3] = ul * kld;  pr[4] = ul * rec;  pr[5] = ul * kcat;
        pr[6] = lf * addt;
    }
}

__global__ __launch_bounds__(256) void k_final(const float* __restrict__ part,
                                               float* __restrict__ out)
{
    const int oo = blockIdx.x;
    float s = 0.f;
    for (int b = threadIdx.x; b < T; b += 256) s += part[(size_t)b * 7 + oo];
#pragma unroll
    for (int d = 1; d < 64; d <<= 1) s += __shfl_xor(s, d);
    __shared__ float l[4];
    if ((threadIdx.x & 63) == 0) l[threadIdx.x >> 6] = s;
    __syncthreads();
    if (threadIdx.x == 0) out[oo] = (l[0] + l[1]) + (l[2] + l[3]);
}

extern "C" void kernel_launch(void* const* d_in, const int* in_sizes, int n_in,
                              void* d_out, int out_size, void* d_ws, size_t ws_size,
                              hipStream_t stream) {
    (void)in_sizes; (void)n_in; (void)out_size; (void)ws_size;
    const float* x    = (const float*)d_in[0];
    const float* yin  = (const float*)d_in[1];
    const float* ez   = (const float*)d_in[2];
    const float* eu   = (const float*)d_in[3];
    const float* Wpz  = (const float*)d_in[4];
    const float* Wpzm = (const float*)d_in[5];
    const float* Wpzs = (const float*)d_in[6];
    const float* Wpy  = (const float*)d_in[7];
    const float* ppr  = (const float*)d_in[8];
    const float* Wqy  = (const float*)d_in[9];
    const float* qpr  = (const float*)d_in[10];
    const float* Wenc = (const float*)d_in[11];
    const float* Wem  = (const float*)d_in[12];
    const float* Wes  = (const float*)d_in[13];
    const float* Wd   = (const float*)d_in[14];
    const float* Wdm  = (const float*)d_in[15];
    const float* Wds  = (const float*)d_in[16];
    const float* Wih  = (const float*)d_in[17];
    const float* Whh  = (const float*)d_in[18];

    float* ws = (float*)d_ws;
    float* Aq    = ws;                           // T*256
    float* Ae    = Aq    + (size_t)T * 256;      // T*256
    float* Ah    = Ae    + (size_t)T * 256;      // T*128
    float* h_st  = Ah    + (size_t)T * 128;      // T*128
    float* z_st  = h_st  + (size_t)T * 128;      // T*64
    float* em_st = z_st  + (size_t)T * 64;       // T*64
    float* es_st = em_st + (size_t)T * 64;       // T*64
    float* y_st  = es_st + (size_t)T * 64;       // T
    float* part  = y_st  + (size_t)T;            // T*7
    float* leu   = part  + (size_t)T * 7;        // T
    float* WqT   = leu   + (size_t)T;            // 512*64 = 32768

    k_pre<<<T / 16, 256, 0, stream>>>(x, eu, Wqy, Wenc, Wih, Aq, Ae, Ah, leu, WqT);
    k_scan<<<1, 512, 0, stream>>>(qpr, Wenc, Wem, Wes, Wih, Whh,
                                  yin, leu, ez, Aq, Ae, Ah, WqT,
                                  h_st, z_st, em_st, es_st, y_st);
    k_post<<<T, 256, 0, stream>>>(x, yin, Wpz, Wpzm, Wpzs, Wpy, ppr, Wqy, qpr,
                                  Wd, Wdm, Wds, Aq, h_st, z_st, em_st, es_st,
                                  y_st, part);
    k_final<<<7, 256, 0, stream>>>(part, (float*)d_out);
}

// Round 10
// 40097.739 us; speedup vs baseline: 5.8405x; 1.9957x over previous
//
#include <hip/hip_runtime.h>
#include <math.h>

#define T 16384

typedef float f32x4  __attribute__((ext_vector_type(4)));
typedef float f32x16 __attribute__((ext_vector_type(16)));

__device__ __forceinline__ float softplusf_(float x) {
    return (x > 15.f) ? x : __logf(1.f + __expf(x));
}
__device__ __forceinline__ float sigmoidf_(float x) {
    return 1.f / (1.f + __expf(-x));
}
__device__ __forceinline__ float tanh_fast(float x) {
    float xc = fminf(fmaxf(x, -15.f), 15.f);
    float e = __expf(2.f * xc);
    return (e - 1.f) / (e + 1.f);
}

// 16-wide dot-step, 4 accumulators, acc i takes lanes k%4==i (r1/r3/r5
// summation order — DO NOT REORDER).
#define D16(A0,A1,A2,A3,HB,OFF,W) do{ \
  A0=fmaf((HB)[(OFF)+0],(W)[0],A0);  A1=fmaf((HB)[(OFF)+1],(W)[1],A1); \
  A2=fmaf((HB)[(OFF)+2],(W)[2],A2);  A3=fmaf((HB)[(OFF)+3],(W)[3],A3); \
  A0=fmaf((HB)[(OFF)+4],(W)[4],A0);  A1=fmaf((HB)[(OFF)+5],(W)[5],A1); \
  A2=fmaf((HB)[(OFF)+6],(W)[6],A2);  A3=fmaf((HB)[(OFF)+7],(W)[7],A3); \
  A0=fmaf((HB)[(OFF)+8],(W)[8],A0);  A1=fmaf((HB)[(OFF)+9],(W)[9],A1); \
  A2=fmaf((HB)[(OFF)+10],(W)[10],A2); A3=fmaf((HB)[(OFF)+11],(W)[11],A3); \
  A0=fmaf((HB)[(OFF)+12],(W)[12],A0); A1=fmaf((HB)[(OFF)+13],(W)[13],A1); \
  A2=fmaf((HB)[(OFF)+14],(W)[14],A2); A3=fmaf((HB)[(OFF)+15],(W)[15],A3); \
}while(0)

#define SET16(V,G,B) do{ \
  V[0]=G((B)+0);  V[1]=G((B)+1);  V[2]=G((B)+2);  V[3]=G((B)+3); \
  V[4]=G((B)+4);  V[5]=G((B)+5);  V[6]=G((B)+6);  V[7]=G((B)+7); \
  V[8]=G((B)+8);  V[9]=G((B)+9);  V[10]=G((B)+10); V[11]=G((B)+11); \
  V[12]=G((B)+12); V[13]=G((B)+13); V[14]=G((B)+14); V[15]=G((B)+15); \
}while(0)

// ---------------------------------------------------------------------------
// Precompute x-dependent matvec parts + logit(eps_u) (fully parallel).
// Stream outputs stored nontemporal (touch-once; keep L2 clean).
// ---------------------------------------------------------------------------
__global__ __launch_bounds__(256) void k_pre(
    const float* __restrict__ x, const float* __restrict__ eu_g,
    const float* __restrict__ Wqy, const float* __restrict__ Wenc,
    const float* __restrict__ Wih,
    float* __restrict__ Aq, float* __restrict__ Ae, float* __restrict__ Ah,
    float* __restrict__ leu_g)
{
    __shared__ float xs[16 * 128];
    const int t0 = blockIdx.x * 16;
    for (int r = threadIdx.x; r < 16 * 128; r += 256) xs[r] = x[t0 * 128 + r];
    __syncthreads();
    const int j = threadIdx.x;
    if (j < 16) {
        float eu = eu_g[t0 + j];
        leu_g[t0 + j] = __logf(eu) - __logf(1.f - eu);
    }
    for (int tt = 0; tt < 16; ++tt) {
        float aq = 0.f, ae = 0.f;
#pragma unroll 8
        for (int i = 0; i < 128; ++i) {
            float xv = xs[tt * 128 + i];
            aq = fmaf(xv, Wqy[i * 256 + j], aq);
            ae = fmaf(xv, Wenc[i * 256 + j], ae);
        }
        __builtin_nontemporal_store(aq, &Aq[(size_t)(t0 + tt) * 256 + j]);
        __builtin_nontemporal_store(ae, &Ae[(size_t)(t0 + tt) * 256 + j]);
    }
    if (j < 128) {
        for (int tt = 0; tt < 16; ++tt) {
            float ah = 0.f;
#pragma unroll 8
            for (int i = 0; i < 128; ++i)
                ah = fmaf(xs[tt * 128 + i], Wih[(65 + i) * 128 + j], ah);
            __builtin_nontemporal_store(ah, &Ah[(size_t)(t0 + tt) * 128 + j]);
        }
    }
}

// ---------------------------------------------------------------------------
// Sequential scan (r5 structure, arithmetic frozen). Streams are loaded
// NONTEMPORAL and trajectory stored NONTEMPORAL so the compiler's scratch
// (spilled weights, ~360 KB) stays L2-resident — that scratch reload is the
// measured per-step bottleneck (~62 B/cy/CU).
// ---------------------------------------------------------------------------
__global__
__attribute__((amdgpu_flat_work_group_size(512, 512)))
__attribute__((amdgpu_waves_per_eu(2, 2)))
void k_scan(
    const float* __restrict__ Wqy, const float* __restrict__ qpr,
    const float* __restrict__ Wenc,
    const float* __restrict__ Wem0, const float* __restrict__ Wes0,
    const float* __restrict__ Wih, const float* __restrict__ Whh,
    const float* __restrict__ yin_g, const float* __restrict__ leu_g,
    const float* __restrict__ ez_g,
    const float* __restrict__ Aq, const float* __restrict__ Ae,
    const float* __restrict__ Ah,
    float* __restrict__ h_st, float* __restrict__ z_st,
    float* __restrict__ em_st, float* __restrict__ es_st,
    float* __restrict__ y_st)
{
    const int tid = threadIdx.x;
    const int j   = tid >> 1, c1 = tid & 1;              // S1/S3 mapping
    const int m4  = tid >> 3; const int k4s = (tid >> 2) & 1; const int c4 = tid & 3; // S4
    const int o5  = tid >> 2, c5 = tid & 3;              // S5

    // ---- LDS (~153.5 KB) ----
    __shared__ __align__(16) f32x4 wq4[16][512];         // 128 KB: W_q_y h-part
    __shared__ __align__(16) float s_aq[4][256];
    __shared__ __align__(16) float s_ae[4][256];
    __shared__ __align__(16) float s_ah[4][128];
    __shared__ __align__(16) float s_ez[4][64];
    __shared__ __align__(16) float s_yin[4];
    __shared__ __align__(16) float s_leu[4];
    __shared__ __align__(16) float t_h[4][128];
    __shared__ __align__(16) float t_z[4][64];
    __shared__ __align__(16) float t_em[4][64];
    __shared__ __align__(16) float t_es[4][64];
    __shared__ float t_y[4];
    __shared__ __align__(16) float h_lds[2][128];
    __shared__ __align__(16) float h5c[2][4][132];       // padded replicas
    __shared__ __align__(16) float eh4[4][260];          // padded replicas
    __shared__ __align__(16) float z_lds[64];
    __shared__ float red[8];

    // ---- persistent weights (compiler will spill; scratch stays L2-hot) ----
    f32x16 weh0, weh1, weh2, weh3, wms0, wms1, wms2, wms3, wh5a, wh5b, wz5v;
    {
        auto ge = [&](int k) { return Wenc[(129 + c1 * 64 + k) * 256 + j]; };
        SET16(weh0, ge, 0); SET16(weh1, ge, 16); SET16(weh2, ge, 32); SET16(weh3, ge, 48);
    }
    const float wey = Wenc[128 * 256 + j];
    const float qpj = qpr[j];
    {
        const float* Wm = k4s ? Wes0 : Wem0;
        auto gm = [&](int k) { return Wm[(c4 * 64 + k) * 64 + m4]; };
        SET16(wms0, gm, 0); SET16(wms1, gm, 16); SET16(wms2, gm, 32); SET16(wms3, gm, 48);
    }
    {
        auto gh = [&](int k) { return Whh[(c5 * 32 + k) * 128 + o5]; };
        SET16(wh5a, gh, 0); SET16(wh5b, gh, 16);
    }
    {
        auto gz = [&](int k) { return Wih[(1 + c5 * 16 + k) * 128 + o5]; };
        SET16(wz5v, gz, 0);
    }
    const float wihy = Wih[o5];

    // W_q_y h-part -> LDS, thread-major float4 (lane-consecutive => no conflicts)
    for (int kq = 0; kq < 16; ++kq) {
        f32x4 v;
        v[0] = Wqy[(128 + c1 * 64 + 4 * kq + 0) * 256 + j];
        v[1] = Wqy[(128 + c1 * 64 + 4 * kq + 1) * 256 + j];
        v[2] = Wqy[(128 + c1 * 64 + 4 * kq + 2) * 256 + j];
        v[3] = Wqy[(128 + c1 * 64 + 4 * kq + 3) * 256 + j];
        wq4[kq][tid] = v;
    }
    if (tid < 128) {
        h_lds[0][tid] = 0.f; h_lds[1][tid] = 0.f;
        h5c[0][0][tid] = 0.f; h5c[0][1][tid] = 0.f;
        h5c[0][2][tid] = 0.f; h5c[0][3][tid] = 0.f;
    }

    // ---- async batch staging: global -> regs (early, NT) -> LDS (late) ----
    f32x4 pA, pC;
    auto load_regs = [&](int t0) {
        if (tid < 256) pA = __builtin_nontemporal_load(((const f32x4*)(Aq + (size_t)t0 * 256)) + tid);
        else           pA = __builtin_nontemporal_load(((const f32x4*)(Ae + (size_t)t0 * 256)) + (tid - 256));
        if (tid < 128)       pC = __builtin_nontemporal_load(((const f32x4*)(Ah + (size_t)t0 * 128)) + tid);
        else if (tid < 192)  pC = __builtin_nontemporal_load(((const f32x4*)(ez_g + (size_t)t0 * 64)) + (tid - 128));
        else if (tid == 192) pC = __builtin_nontemporal_load((const f32x4*)(yin_g + t0));
        else if (tid == 193) pC = __builtin_nontemporal_load((const f32x4*)(leu_g + t0));
    };
    auto write_regs = [&]() {
        if (tid < 256) ((f32x4*)&s_aq[0][0])[tid] = pA;
        else           ((f32x4*)&s_ae[0][0])[tid - 256] = pA;
        if (tid < 128)       ((f32x4*)&s_ah[0][0])[tid] = pC;
        else if (tid < 192)  ((f32x4*)&s_ez[0][0])[tid - 128] = pC;
        else if (tid == 192) *(f32x4*)s_yin = pC;
        else if (tid == 193) *(f32x4*)s_leu = pC;
    };
    auto flushb = [&](int t0) {
        if (tid < 128) {
            __builtin_nontemporal_store(((const f32x4*)&t_h[0][0])[tid],
                                        ((f32x4*)(h_st + (size_t)t0 * 128)) + tid);
        } else if (tid < 192) {
            __builtin_nontemporal_store(((const f32x4*)&t_z[0][0])[tid - 128],
                                        ((f32x4*)(z_st + (size_t)t0 * 64)) + (tid - 128));
        } else if (tid < 256) {
            __builtin_nontemporal_store(((const f32x4*)&t_em[0][0])[tid - 192],
                                        ((f32x4*)(em_st + (size_t)t0 * 64)) + (tid - 192));
        } else if (tid < 320) {
            __builtin_nontemporal_store(((const f32x4*)&t_es[0][0])[tid - 256],
                                        ((f32x4*)(es_st + (size_t)t0 * 64)) + (tid - 256));
        } else if (tid < 324) {
            __builtin_nontemporal_store(t_y[tid - 320], &y_st[t0 + (tid - 320)]);
        }
    };

    // prologue: stage batch 0
    load_regs(0);
    write_regs();
    __syncthreads();

    for (int t0 = 0; t0 < T; t0 += 4) {
        const int tnb = (t0 + 4 < T) ? t0 + 4 : t0;
        load_regs(tnb);                                    // issue early (T14)

        for (int tt = 0; tt < 4; ++tt) {
            const int t = t0 + tt;
            const int cur = t & 1, nxt = cur ^ 1;
            const float aq  = s_aq[tt][j];
            const float ae  = s_ae[tt][j];
            const float yin = s_yin[tt];
            const float leu = s_leu[tt];
            const float ez  = s_ez[tt][m4];
            const float ah  = s_ah[tt][o5];
            const float* __restrict__ hb = &h_lds[cur][c1 * 64];

            float y_t;
            if (yin == -1.0f) {   // unlabeled (block-uniform branch)
                float a0 = 0.f, a1 = 0.f, a2 = 0.f, a3 = 0.f;
#pragma unroll
                for (int kq = 0; kq < 16; ++kq) {
                    f32x4 w = wq4[kq][tid];
                    a0 = fmaf(hb[4 * kq + 0], w[0], a0);
                    a1 = fmaf(hb[4 * kq + 1], w[1], a1);
                    a2 = fmaf(hb[4 * kq + 2], w[2], a2);
                    a3 = fmaf(hb[4 * kq + 3], w[3], a3);
                }
                float s = (a0 + a1) + (a2 + a3);
                s += __shfl_xor(s, 1);
                float qh = fmaxf(aq + s, 0.f);
                float cq = (c1 == 0) ? qh * qpj : 0.f;
#pragma unroll
                for (int d = 1; d < 64; d <<= 1) cq += __shfl_xor(cq, d);
                if ((tid & 63) == 0) red[tid >> 6] = cq;
                __syncthreads();                           // B1
                float qlog = ((red[0] + red[1]) + (red[2] + red[3])) +
                             ((red[4] + red[5]) + (red[6] + red[7]));
                y_t = sigmoidf_(leu + qlog);
            } else {
                y_t = yin;
            }

            // S3: eh = relu(Ae + y*wey + h @ We_h)
            {
                float e0 = 0.f, e1 = 0.f, e2 = 0.f, e3 = 0.f;
                D16(e0, e1, e2, e3, hb, 0,  weh0);
                D16(e0, e1, e2, e3, hb, 16, weh1);
                D16(e0, e1, e2, e3, hb, 32, weh2);
                D16(e0, e1, e2, e3, hb, 48, weh3);
                float ehs = (e0 + e1) + (e2 + e3);
                ehs += __shfl_xor(ehs, 1);
                float eh = fmaxf(fmaf(y_t, wey, ae) + ehs, 0.f);
                if (c1 == 0) {
                    eh4[0][j] = eh; eh4[1][j] = eh; eh4[2][j] = eh; eh4[3][j] = eh;
                }
            }
            __syncthreads();                               // B3

            // S4: em/es = eh @ W_enc_mean/std ; z = ez*softplus(es)+em
            {
                const float* __restrict__ eb = &eh4[c4][c4 * 64];
                float b0 = 0.f, b1 = 0.f, b2 = 0.f, b3 = 0.f;
                D16(b0, b1, b2, b3, eb, 0,  wms0);
                D16(b0, b1, b2, b3, eb, 16, wms1);
                D16(b0, b1, b2, b3, eb, 32, wms2);
                D16(b0, b1, b2, b3, eb, 48, wms3);
                float s = (b0 + b1) + (b2 + b3);
                s += __shfl_xor(s, 1);
                s += __shfl_xor(s, 2);
                float other = __shfl_xor(s, 4);
                float em_pre = k4s ? other : s;
                float es_pre = k4s ? s : other;
                float es = softplusf_(es_pre);
                float zm = fmaf(ez, es, em_pre);
                if ((tid & 7) == 0) {
                    z_lds[m4] = zm;
                    t_z[tt][m4] = zm; t_em[tt][m4] = em_pre; t_es[tt][m4] = es;
                }
            }
            __syncthreads();                               // B4

            // S5: h_new = tanh(Ah + y*wihy + z @ Wih_z + h @ W_hh)
            {
                const float* __restrict__ zb  = &z_lds[c5 * 16];
                const float* __restrict__ hb5 = &h5c[cur][c5][c5 * 32];
                float g0 = 0.f, g1 = 0.f, g2 = 0.f, g3 = 0.f;
                D16(g0, g1, g2, g3, zb, 0, wz5v);
                D16(g0, g1, g2, g3, hb5, 0,  wh5a);
                D16(g0, g1, g2, g3, hb5, 16, wh5b);
                float s = (g0 + g1) + (g2 + g3);
                s += __shfl_xor(s, 1);
                s += __shfl_xor(s, 2);
                float hn = tanh_fast(fmaf(y_t, wihy, ah) + s);
                if (c5 == 0) {
                    h_lds[nxt][o5] = hn;
                    h5c[nxt][0][o5] = hn; h5c[nxt][1][o5] = hn;
                    h5c[nxt][2][o5] = hn; h5c[nxt][3][o5] = hn;
                    t_h[tt][o5] = hn;
                }
                if (tid == 0) t_y[tt] = y_t;
            }
            __syncthreads();                               // B5
        }

        flushb(t0);            // trajectory for this batch (t_* complete, NT)
        write_regs();          // s_* for next batch (loads long in flight)
        __syncthreads();       // batch barrier
    }
}

// ---------------------------------------------------------------------------
// Post-pass: one block per timestep (unchanged).
// ---------------------------------------------------------------------------
__global__ __launch_bounds__(256) void k_post(
    const float* __restrict__ x, const float* __restrict__ yin_g,
    const float* __restrict__ Wpz, const float* __restrict__ Wpzm,
    const float* __restrict__ Wpzs,
    const float* __restrict__ Wpy, const float* __restrict__ ppr,
    const float* __restrict__ Wqy, const float* __restrict__ qpr,
    const float* __restrict__ Wd, const float* __restrict__ Wdm,
    const float* __restrict__ Wds,
    const float* __restrict__ Aq,
    const float* __restrict__ h_st, const float* __restrict__ z_st,
    const float* __restrict__ em_st, const float* __restrict__ es_st,
    const float* __restrict__ y_st,
    float* __restrict__ part)
{
    const float CC = -0.9189385332046727f;  // -0.5*log(2*pi)
    const int t = blockIdx.x;
    const int tid = threadIdx.x;
    __shared__ float xp[128], xdv[128], xcv[128], hp[128];
    __shared__ float zp[64], ztv[64], emv[64], esv[64];
    __shared__ float pzh[256], dhv[256];
    __shared__ float pmv[64], psv[64], dmv[128], dsv[128];
    __shared__ float rl[16];

    const int tp = t ? (t - 1) : (T - 1);
    if (tid < 128) {
        xp[tid]  = x[(size_t)tp * 128 + tid];
        xdv[tid] = t ? x[(size_t)(t - 1) * 128 + tid] : 0.f;
        xcv[tid] = x[(size_t)t * 128 + tid];
        hp[tid]  = t ? h_st[(size_t)(t - 1) * 128 + tid] : 0.f;
    } else {
        int m = tid - 128;
        if (m < 64) {
            zp[m]  = t ? z_st[(size_t)(t - 1) * 64 + m] : 0.f;
            ztv[m] = z_st[(size_t)t * 64 + m];
        } else {
            m -= 64;
            emv[m] = em_st[(size_t)t * 64 + m];
            esv[m] = es_st[(size_t)t * 64 + m];
        }
    }
    __syncthreads();

    const float y_t = y_st[t];
    const float y_prev = t ? y_st[t - 1] : 0.f;
    const float lf = (yin_g[t] != -1.0f) ? 1.f : 0.f;
    const int jj = tid;

    float ap = 0.f;
#pragma unroll 4
    for (int i = 0; i < 128; ++i) ap = fmaf(xp[i], Wpy[i * 256 + jj], ap);
    ap = fmaf(y_prev, Wpy[128 * 256 + jj], ap);
    float cp = fmaxf(ap, 0.f) * ppr[jj];

    float aqv = Aq[(size_t)t * 256 + jj];
#pragma unroll 4
    for (int i = 0; i < 128; ++i) aqv = fmaf(hp[i], Wqy[(128 + i) * 256 + jj], aqv);
    float cq = fmaxf(aqv, 0.f) * qpr[jj];

    float az = 0.f;
#pragma unroll 4
    for (int m = 0; m < 64; ++m) az = fmaf(zp[m], Wpz[m * 256 + jj], az);
    pzh[jj] = fmaxf(az, 0.f);

    float ad = 0.f;
#pragma unroll 4
    for (int i = 0; i < 128; ++i) ad = fmaf(xdv[i], Wd[i * 256 + jj], ad);
#pragma unroll 4
    for (int m = 0; m < 64; ++m) ad = fmaf(ztv[m], Wd[(128 + m) * 256 + jj], ad);
    ad = fmaf(y_t, Wd[192 * 256 + jj], ad);
    dhv[jj] = fmaxf(ad, 0.f);
    __syncthreads();

    {
        const int i_ = tid & 127;
        const float* W = (tid < 128) ? Wdm : Wds;
        float a = 0.f;
#pragma unroll 4
        for (int q2 = 0; q2 < 256; ++q2) a = fmaf(dhv[q2], W[q2 * 128 + i_], a);
        if (tid < 128) dmv[i_] = a; else dsv[i_] = softplusf_(a);
    }
    if (tid < 128) {
        const int m = tid & 63;
        const float* W = (tid < 64) ? Wpzm : Wpzs;
        float a = 0.f;
#pragma unroll 4
        for (int q2 = 0; q2 < 256; ++q2) a = fmaf(pzh[q2], W[q2 * 64 + m], a);
        if (tid < 64) pmv[m] = a; else psv[m] = softplusf_(a);
    }
    __syncthreads();

    float kldc = 0.f, recc = 0.f;
    if (tid < 64) {
        float es = esv[tid], em = emv[tid], pm = pmv[tid], ps = psv[tid];
        float d = em - pm;
        kldc = __logf(ps / es) + (es * es + d * d) / (2.f * ps * ps) - 0.5f;
    }
    if (tid < 128) {
        float dm = dmv[tid], ds = dsv[tid], xv = xcv[tid];
        float d = xv - dm;
        recc = CC + __logf(ds) + d * d / (2.f * ds * ds);
    }

#pragma unroll
    for (int d = 1; d < 64; d <<= 1) {
        cp += __shfl_xor(cp, d);
        cq += __shfl_xor(cq, d);
        kldc += __shfl_xor(kldc, d);
        recc += __shfl_xor(recc, d);
    }
    if ((tid & 63) == 0) {
        const int w = tid >> 6;
        rl[w * 4 + 0] = cp; rl[w * 4 + 1] = cq;
        rl[w * 4 + 2] = kldc; rl[w * 4 + 3] = recc;
    }
    __syncthreads();
    if (tid == 0) {
        float plog = rl[0] + rl[4] + rl[8]  + rl[12];
        float qlog = rl[1] + rl[5] + rl[9]  + rl[13];
        float kld  = rl[2] + rl[6] + rl[10] + rl[14];
        float rec  = rl[3] + rl[7] + rl[11] + rl[15];
        float p = sigmoidf_(plog), q = sigmoidf_(qlog);
        float bce  = -(y_t * __logf(p) + (1.f - y_t) * __logf(1.f - p));
        float addt = y_t * __logf(p * q) + (1.f - y_t) * __logf((1.f - p) * (1.f - q));
        float kcat = p * __logf(p / q) + (1.f - p) * __logf((1.f - p) / (1.f - q));
        float ul = 1.f - lf;
        float* pr = part + (size_t)t * 7;
        pr[0] = lf * kld;  pr[1] = lf * rec;  pr[2] = lf * bce;
        pr[3] = ul * kld;  pr[4] = ul * rec;  pr[5] = ul * kcat;
        pr[6] = lf * addt;
    }
}

__global__ __launch_bounds__(256) void k_final(const float* __restrict__ part,
                                               float* __restrict__ out)
{
    const int o = blockIdx.x;
    float s = 0.f;
    for (int b = threadIdx.x; b < T; b += 256) s += part[(size_t)b * 7 + o];
#pragma unroll
    for (int d = 1; d < 64; d <<= 1) s += __shfl_xor(s, d);
    __shared__ float l[4];
    if ((threadIdx.x & 63) == 0) l[threadIdx.x >> 6] = s;
    __syncthreads();
    if (threadIdx.x == 0) out[o] = (l[0] + l[1]) + (l[2] + l[3]);
}

extern "C" void kernel_launch(void* const* d_in, const int* in_sizes, int n_in,
                              void* d_out, int out_size, void* d_ws, size_t ws_size,
                              hipStream_t stream) {
    (void)in_sizes; (void)n_in; (void)out_size; (void)ws_size;
    const float* x    = (const float*)d_in[0];
    const float* yin  = (const float*)d_in[1];
    const float* ez   = (const float*)d_in[2];
    const float* eu   = (const float*)d_in[3];
    const float* Wpz  = (const float*)d_in[4];
    const float* Wpzm = (const float*)d_in[5];
    const float* Wpzs = (const float*)d_in[6];
    const float* Wpy  = (const float*)d_in[7];
    const float* ppr  = (const float*)d_in[8];
    const float* Wqy  = (const float*)d_in[9];
    const float* qpr  = (const float*)d_in[10];
    const float* Wenc = (const float*)d_in[11];
    const float* Wem  = (const float*)d_in[12];
    const float* Wes  = (const float*)d_in[13];
    const float* Wd   = (const float*)d_in[14];
    const float* Wdm  = (const float*)d_in[15];
    const float* Wds  = (const float*)d_in[16];
    const float* Wih  = (const float*)d_in[17];
    const float* Whh  = (const float*)d_in[18];

    float* ws = (float*)d_ws;
    float* Aq    = ws;                           // T*256
    float* Ae    = Aq    + (size_t)T * 256;      // T*256
    float* Ah    = Ae    + (size_t)T * 256;      // T*128
    float* h_st  = Ah    + (size_t)T * 128;      // T*128
    float* z_st  = h_st  + (size_t)T * 128;      // T*64
    float* em_st = z_st  + (size_t)T * 64;       // T*64
    float* es_st = em_st + (size_t)T * 64;       // T*64
    float* y_st  = es_st + (size_t)T * 64;       // T
    float* part  = y_st  + (size_t)T;            // T*7
    float* leu   = part  + (size_t)T * 7;        // T

    k_pre<<<T / 16, 256, 0, stream>>>(x, eu, Wqy, Wenc, Wih, Aq, Ae, Ah, leu);
    k_scan<<<1, 512, 0, stream>>>(Wqy, qpr, Wenc, Wem, Wes, Wih, Whh,
                                  yin, leu, ez, Aq, Ae, Ah,
                                  h_st, z_st, em_st, es_st, y_st);
    k_post<<<T, 256, 0, stream>>>(x, yin, Wpz, Wpzm, Wpzs, Wpy, ppr, Wqy, qpr,
                                  Wd, Wdm, Wds, Aq, h_st, z_st, em_st, es_st,
                                  y_st, part);
    k_final<<<7, 256, 0, stream>>>(part, (float*)d_out);
}

// Round 11
// 29505.331 us; speedup vs baseline: 7.9373x; 1.3590x over previous
//
#include <hip/hip_runtime.h>
#include <math.h>

#define T 16384

typedef float f32x4 __attribute__((ext_vector_type(4)));
typedef unsigned int u32x4 __attribute__((ext_vector_type(4)));
typedef _Float16 h16x2 __attribute__((ext_vector_type(2)));

__device__ __forceinline__ float softplusf_(float x) {
    return (x > 15.f) ? x : __logf(1.f + __expf(x));
}
__device__ __forceinline__ float sigmoidf_(float x) {
    return 1.f / (1.f + __expf(-x));
}
__device__ __forceinline__ float tanh_fast(float x) {
    float xc = fminf(fmaxf(x, -15.f), 15.f);
    float e = __expf(2.f * xc);
    return (e - 1.f) / (e + 1.f);
}
__device__ __forceinline__ unsigned packf16(float a, float b) {
    h16x2 p; p[0] = (_Float16)a; p[1] = (_Float16)b;   // RTN converts
    return __builtin_bit_cast(unsigned, p);
}
#define H2(u) __builtin_bit_cast(h16x2, (unsigned)(u))
// f32 += f16*f16 + f16*f16 (V_DOT2_F32_F16)
#define DOT2(ACC, UH, UW) ACC = __builtin_amdgcn_fdot2(H2(UH), H2(UW), ACC, false)

// ---------------------------------------------------------------------------
// Precompute x-dependent matvec parts + logit(eps_u) (fully parallel, f32).
// ---------------------------------------------------------------------------
__global__ __launch_bounds__(256) void k_pre(
    const float* __restrict__ x, const float* __restrict__ eu_g,
    const float* __restrict__ Wqy, const float* __restrict__ Wenc,
    const float* __restrict__ Wih,
    float* __restrict__ Aq, float* __restrict__ Ae, float* __restrict__ Ah,
    float* __restrict__ leu_g)
{
    __shared__ float xs[16 * 128];
    const int t0 = blockIdx.x * 16;
    for (int r = threadIdx.x; r < 16 * 128; r += 256) xs[r] = x[t0 * 128 + r];
    __syncthreads();
    const int j = threadIdx.x;
    if (j < 16) {
        float eu = eu_g[t0 + j];
        leu_g[t0 + j] = __logf(eu) - __logf(1.f - eu);
    }
    for (int tt = 0; tt < 16; ++tt) {
        float aq = 0.f, ae = 0.f;
#pragma unroll 8
        for (int i = 0; i < 128; ++i) {
            float xv = xs[tt * 128 + i];
            aq = fmaf(xv, Wqy[i * 256 + j], aq);
            ae = fmaf(xv, Wenc[i * 256 + j], ae);
        }
        Aq[(size_t)(t0 + tt) * 256 + j] = aq;
        Ae[(size_t)(t0 + tt) * 256 + j] = ae;
    }
    if (j < 128) {
        for (int tt = 0; tt < 16; ++tt) {
            float ah = 0.f;
#pragma unroll 8
            for (int i = 0; i < 128; ++i)
                ah = fmaf(xs[tt * 128 + i], Wih[(65 + i) * 128 + j], ah);
            Ah[(size_t)(t0 + tt) * 128 + j] = ah;
        }
    }
}

// ---------------------------------------------------------------------------
// Sequential scan: 1 block x 512 threads. ALL weights f16-packed:
//   LDS : W_q_y-h (64 KB) + W_em/es (64 KB), thread-major u32x4, private slots
//   regs: W_enc-h 32 + W_hh 16 + W_ih-z 8 = 56 VGPRs -> fits 128, no spill
// Dots via v_dot2_f32_f16 (f32 accumulate). Activations packed per step.
// Thread mappings and reduction trees identical to r5.
// ---------------------------------------------------------------------------
__global__
__attribute__((amdgpu_flat_work_group_size(512, 512)))
__attribute__((amdgpu_waves_per_eu(2, 2)))
void k_scan(
    const float* __restrict__ Wqy, const float* __restrict__ qpr,
    const float* __restrict__ Wenc,
    const float* __restrict__ Wem0, const float* __restrict__ Wes0,
    const float* __restrict__ Wih, const float* __restrict__ Whh,
    const float* __restrict__ yin_g, const float* __restrict__ leu_g,
    const float* __restrict__ ez_g,
    const float* __restrict__ Aq, const float* __restrict__ Ae,
    const float* __restrict__ Ah,
    float* __restrict__ h_st, float* __restrict__ z_st,
    float* __restrict__ em_st, float* __restrict__ es_st,
    float* __restrict__ y_st)
{
    const int tid = threadIdx.x;
    const int j   = tid >> 1, c1 = tid & 1;                          // S1/S3
    const int m4  = tid >> 3; const int k4s = (tid >> 2) & 1; const int c4 = tid & 3; // S4
    const int o5  = tid >> 2, c5 = tid & 3;                          // S5

    // ---- LDS (~145 KB) ----
    __shared__ __align__(16) u32x4 wq2[8][512];      // 64 KB W_q_y h-part (f16)
    __shared__ __align__(16) u32x4 wm2[8][512];      // 64 KB W_em/es (f16)
    __shared__ __align__(16) float s_aq[4][256];
    __shared__ __align__(16) float s_ae[4][256];
    __shared__ __align__(16) float s_ah[4][128];
    __shared__ __align__(16) float s_ez[4][64];
    __shared__ __align__(16) float s_yin[4];
    __shared__ __align__(16) float s_leu[4];
    __shared__ __align__(16) float t_h[4][128];
    __shared__ __align__(16) float t_z[4][64];
    __shared__ __align__(16) float t_em[4][64];
    __shared__ __align__(16) float t_es[4][64];
    __shared__ float t_y[4];
    __shared__ __align__(16) unsigned hh2[2][64];    // h packed (f16 pairs)
    __shared__ __align__(16) unsigned eh2[128];      // eh packed
    __shared__ __align__(16) unsigned z2[32];        // z packed
    __shared__ float red[8];

    // ---- register weights (f16-packed u32, constant indices) ----
    unsigned weh2_[32];                              // W_enc-h chunk (64 f)
#pragma unroll
    for (int g = 0; g < 8; ++g)
#pragma unroll
        for (int e = 0; e < 4; ++e) {
            const int k = g * 8 + 2 * e;
            weh2_[g * 4 + e] = packf16(Wenc[(129 + c1 * 64 + k) * 256 + j],
                                       Wenc[(129 + c1 * 64 + k + 1) * 256 + j]);
        }
    unsigned wh2_[16];                               // W_hh chunk (32 f)
#pragma unroll
    for (int g = 0; g < 4; ++g)
#pragma unroll
        for (int e = 0; e < 4; ++e) {
            const int k = g * 8 + 2 * e;
            wh2_[g * 4 + e] = packf16(Whh[(c5 * 32 + k) * 128 + o5],
                                      Whh[(c5 * 32 + k + 1) * 128 + o5]);
        }
    unsigned wz2_[8];                                // W_ih-z chunk (16 f)
#pragma unroll
    for (int p = 0; p < 8; ++p)
        wz2_[p] = packf16(Wih[(1 + c5 * 16 + 2 * p) * 128 + o5],
                          Wih[(1 + c5 * 16 + 2 * p + 1) * 128 + o5]);
    const float wey  = Wenc[128 * 256 + j];
    const float qpj  = qpr[j];
    const float wihy = Wih[o5];

    // ---- LDS weights: W_q_y h-part + W_em/es, thread-major ----
    for (int g = 0; g < 8; ++g) {
        u32x4 v;
#pragma unroll
        for (int e = 0; e < 4; ++e) {
            const int k = g * 8 + 2 * e;
            v[e] = packf16(Wqy[(128 + c1 * 64 + k) * 256 + j],
                           Wqy[(128 + c1 * 64 + k + 1) * 256 + j]);
        }
        wq2[g][tid] = v;
    }
    {
        const float* Wm = k4s ? Wes0 : Wem0;
        for (int g = 0; g < 8; ++g) {
            u32x4 v;
#pragma unroll
            for (int e = 0; e < 4; ++e) {
                const int k = g * 8 + 2 * e;
                v[e] = packf16(Wm[(c4 * 64 + k) * 64 + m4],
                               Wm[(c4 * 64 + k + 1) * 64 + m4]);
            }
            wm2[g][tid] = v;
        }
    }
    if (tid < 64) hh2[0][tid] = 0u;                  // h(0) = 0

    // ---- staging: global -> regs (early) -> LDS (late) ----
    f32x4 pA, pC;
    auto load_regs = [&](int t0) {
        if (tid < 256) pA = ((const f32x4*)(Aq + (size_t)t0 * 256))[tid];
        else           pA = ((const f32x4*)(Ae + (size_t)t0 * 256))[tid - 256];
        if (tid < 128)       pC = ((const f32x4*)(Ah + (size_t)t0 * 128))[tid];
        else if (tid < 192)  pC = ((const f32x4*)(ez_g + (size_t)t0 * 64))[tid - 128];
        else if (tid == 192) pC = *(const f32x4*)(yin_g + t0);
        else if (tid == 193) pC = *(const f32x4*)(leu_g + t0);
    };
    auto write_regs = [&]() {
        if (tid < 256) ((f32x4*)&s_aq[0][0])[tid] = pA;
        else           ((f32x4*)&s_ae[0][0])[tid - 256] = pA;
        if (tid < 128)       ((f32x4*)&s_ah[0][0])[tid] = pC;
        else if (tid < 192)  ((f32x4*)&s_ez[0][0])[tid - 128] = pC;
        else if (tid == 192) *(f32x4*)s_yin = pC;
        else if (tid == 193) *(f32x4*)s_leu = pC;
    };
    auto flushb = [&](int t0) {
        if (tid < 128) {
            ((f32x4*)(h_st + (size_t)t0 * 128))[tid] = ((const f32x4*)&t_h[0][0])[tid];
        } else if (tid < 192) {
            ((f32x4*)(z_st + (size_t)t0 * 64))[tid - 128] = ((const f32x4*)&t_z[0][0])[tid - 128];
        } else if (tid < 256) {
            ((f32x4*)(em_st + (size_t)t0 * 64))[tid - 192] = ((const f32x4*)&t_em[0][0])[tid - 192];
        } else if (tid < 320) {
            ((f32x4*)(es_st + (size_t)t0 * 64))[tid - 256] = ((const f32x4*)&t_es[0][0])[tid - 256];
        } else if (tid < 324) {
            y_st[t0 + (tid - 320)] = t_y[tid - 320];
        }
    };

    load_regs(0);
    write_regs();
    __syncthreads();

    for (int t0 = 0; t0 < T; t0 += 4) {
        const int tnb = (t0 + 4 < T) ? t0 + 4 : t0;
        load_regs(tnb);                                    // issue early (T14)

        for (int tt = 0; tt < 4; ++tt) {
            const int t = t0 + tt;
            const int cur = t & 1, nxt = cur ^ 1;
            const float aq  = s_aq[tt][j];
            const float ae  = s_ae[tt][j];
            const float yin = s_yin[tt];
            const float leu = s_leu[tt];
            const float ezv = s_ez[tt][m4];
            const float ahv = s_ah[tt][o5];
            const u32x4* __restrict__ hh4 = (const u32x4*)&hh2[cur][0];

            float y_t, ehdot;
            if (yin == -1.0f) {
                // fused q-dot (LDS f16) + eh-dot (reg f16), shared h pairs
                float a0 = 0.f, a1 = 0.f, e0 = 0.f, e1 = 0.f;
#pragma unroll
                for (int g = 0; g < 8; ++g) {
                    u32x4 hv = hh4[c1 * 8 + g];
                    u32x4 qv = wq2[g][tid];
                    DOT2(a0, hv[0], qv[0]); DOT2(a1, hv[1], qv[1]);
                    DOT2(a0, hv[2], qv[2]); DOT2(a1, hv[3], qv[3]);
                    DOT2(e0, hv[0], weh2_[g * 4 + 0]);
                    DOT2(e1, hv[1], weh2_[g * 4 + 1]);
                    DOT2(e0, hv[2], weh2_[g * 4 + 2]);
                    DOT2(e1, hv[3], weh2_[g * 4 + 3]);
                }
                float s = a0 + a1;
                ehdot   = e0 + e1;
                s += __shfl_xor(s, 1);
                ehdot += __shfl_xor(ehdot, 1);
                float qh = fmaxf(aq + s, 0.f);
                float cq = (c1 == 0) ? qh * qpj : 0.f;
#pragma unroll
                for (int d = 1; d < 64; d <<= 1) cq += __shfl_xor(cq, d);
                if ((tid & 63) == 0) red[tid >> 6] = cq;
                __syncthreads();                           // B1
                float qlog = ((red[0] + red[1]) + (red[2] + red[3])) +
                             ((red[4] + red[5]) + (red[6] + red[7]));
                y_t = sigmoidf_(leu + qlog);
            } else {
                float e0 = 0.f, e1 = 0.f;
#pragma unroll
                for (int g = 0; g < 8; ++g) {
                    u32x4 hv = hh4[c1 * 8 + g];
                    DOT2(e0, hv[0], weh2_[g * 4 + 0]);
                    DOT2(e1, hv[1], weh2_[g * 4 + 1]);
                    DOT2(e0, hv[2], weh2_[g * 4 + 2]);
                    DOT2(e1, hv[3], weh2_[g * 4 + 3]);
                }
                ehdot = e0 + e1;
                ehdot += __shfl_xor(ehdot, 1);
                y_t = yin;
            }

            // S3 finalize: eh = relu(Ae + y*wey + h-dot); pack pairs
            {
                float eh = fmaxf(fmaf(y_t, wey, ae) + ehdot, 0.f);
                float epart = __shfl_xor(eh, 2);           // j^1 partner
                if ((tid & 3) == 0) eh2[j >> 1] = packf16(eh, epart);
            }
            __syncthreads();                               // B3

            // S4: em/es over eh(256); z = ez*softplus(es)+em
            {
                const u32x4* __restrict__ eb4 = (const u32x4*)eh2;
                float b0 = 0.f, b1 = 0.f;
#pragma unroll
                for (int g = 0; g < 8; ++g) {
                    u32x4 ev = eb4[c4 * 8 + g];
                    u32x4 wv = wm2[g][tid];
                    DOT2(b0, ev[0], wv[0]); DOT2(b1, ev[1], wv[1]);
                    DOT2(b0, ev[2], wv[2]); DOT2(b1, ev[3], wv[3]);
                }
                float s = b0 + b1;
                s += __shfl_xor(s, 1);
                s += __shfl_xor(s, 2);
                float other = __shfl_xor(s, 4);
                float em_pre = k4s ? other : s;
                float es_pre = k4s ? s : other;
                float es = softplusf_(es_pre);
                float zm = fmaf(ezv, es, em_pre);
                float zpart = __shfl_xor(zm, 8);           // m4^1 partner
                if ((tid & 7) == 0) {
                    t_z[tt][m4] = zm; t_em[tt][m4] = em_pre; t_es[tt][m4] = es;
                }
                if ((tid & 15) == 0) z2[m4 >> 1] = packf16(zm, zpart);
            }
            __syncthreads();                               // B4

            // S5: h' = tanh(Ah + y*wihy + z@Wih_z + h@W_hh); pack pairs
            {
                const u32x4* __restrict__ zb4 = (const u32x4*)z2;
                float g0 = 0.f, g1 = 0.f;
#pragma unroll
                for (int g = 0; g < 2; ++g) {
                    u32x4 zv = zb4[c5 * 2 + g];
                    DOT2(g0, zv[0], wz2_[g * 4 + 0]);
                    DOT2(g1, zv[1], wz2_[g * 4 + 1]);
                    DOT2(g0, zv[2], wz2_[g * 4 + 2]);
                    DOT2(g1, zv[3], wz2_[g * 4 + 3]);
                }
#pragma unroll
                for (int g = 0; g < 4; ++g) {
                    u32x4 hv = hh4[c5 * 4 + g];
                    DOT2(g0, hv[0], wh2_[g * 4 + 0]);
                    DOT2(g1, hv[1], wh2_[g * 4 + 1]);
                    DOT2(g0, hv[2], wh2_[g * 4 + 2]);
                    DOT2(g1, hv[3], wh2_[g * 4 + 3]);
                }
                float s = g0 + g1;
                s += __shfl_xor(s, 1);
                s += __shfl_xor(s, 2);
                float hn = tanh_fast(fmaf(y_t, wihy, ahv) + s);
                float hpart = __shfl_xor(hn, 4);           // o5^1 partner
                if (c5 == 0) t_h[tt][o5] = hn;
                if ((tid & 7) == 0) hh2[nxt][o5 >> 1] = packf16(hn, hpart);
                if (tid == 0) t_y[tt] = y_t;
            }
            __syncthreads();                               // B5
        }

        flushb(t0);            // trajectory for this batch
        write_regs();          // s_* for next batch (loads long in flight)
        __syncthreads();       // batch barrier
    }
}

// ---------------------------------------------------------------------------
// Post-pass: one block per timestep (unchanged, full f32).
// ---------------------------------------------------------------------------
__global__ __launch_bounds__(256) void k_post(
    const float* __restrict__ x, const float* __restrict__ yin_g,
    const float* __restrict__ Wpz, const float* __restrict__ Wpzm,
    const float* __restrict__ Wpzs,
    const float* __restrict__ Wpy, const float* __restrict__ ppr,
    const float* __restrict__ Wqy, const float* __restrict__ qpr,
    const float* __restrict__ Wd, const float* __restrict__ Wdm,
    const float* __restrict__ Wds,
    const float* __restrict__ Aq,
    const float* __restrict__ h_st, const float* __restrict__ z_st,
    const float* __restrict__ em_st, const float* __restrict__ es_st,
    const float* __restrict__ y_st,
    float* __restrict__ part)
{
    const float CC = -0.9189385332046727f;  // -0.5*log(2*pi)
    const int t = blockIdx.x;
    const int tid = threadIdx.x;
    __shared__ float xp[128], xdv[128], xcv[128], hp[128];
    __shared__ float zp[64], ztv[64], emv[64], esv[64];
    __shared__ float pzh[256], dhv[256];
    __shared__ float pmv[64], psv[64], dmv[128], dsv[128];
    __shared__ float rl[16];

    const int tp = t ? (t - 1) : (T - 1);
    if (tid < 128) {
        xp[tid]  = x[(size_t)tp * 128 + tid];
        xdv[tid] = t ? x[(size_t)(t - 1) * 128 + tid] : 0.f;
        xcv[tid] = x[(size_t)t * 128 + tid];
        hp[tid]  = t ? h_st[(size_t)(t - 1) * 128 + tid] : 0.f;
    } else {
        int m = tid - 128;
        if (m < 64) {
            zp[m]  = t ? z_st[(size_t)(t - 1) * 64 + m] : 0.f;
            ztv[m] = z_st[(size_t)t * 64 + m];
        } else {
            m -= 64;
            emv[m] = em_st[(size_t)t * 64 + m];
            esv[m] = es_st[(size_t)t * 64 + m];
        }
    }
    __syncthreads();

    const float y_t = y_st[t];
    const float y_prev = t ? y_st[t - 1] : 0.f;
    const float lf = (yin_g[t] != -1.0f) ? 1.f : 0.f;
    const int jj = tid;

    float ap = 0.f;
#pragma unroll 4
    for (int i = 0; i < 128; ++i) ap = fmaf(xp[i], Wpy[i * 256 + jj], ap);
    ap = fmaf(y_prev, Wpy[128 * 256 + jj], ap);
    float cp = fmaxf(ap, 0.f) * ppr[jj];

    float aqv = Aq[(size_t)t * 256 + jj];
#pragma unroll 4
    for (int i = 0; i < 128; ++i) aqv = fmaf(hp[i], Wqy[(128 + i) * 256 + jj], aqv);
    float cq = fmaxf(aqv, 0.f) * qpr[jj];

    float az = 0.f;
#pragma unroll 4
    for (int m = 0; m < 64; ++m) az = fmaf(zp[m], Wpz[m * 256 + jj], az);
    pzh[jj] = fmaxf(az, 0.f);

    float ad = 0.f;
#pragma unroll 4
    for (int i = 0; i < 128; ++i) ad = fmaf(xdv[i], Wd[i * 256 + jj], ad);
#pragma unroll 4
    for (int m = 0; m < 64; ++m) ad = fmaf(ztv[m], Wd[(128 + m) * 256 + jj], ad);
    ad = fmaf(y_t, Wd[192 * 256 + jj], ad);
    dhv[jj] = fmaxf(ad, 0.f);
    __syncthreads();

    {
        const int i_ = tid & 127;
        const float* W = (tid < 128) ? Wdm : Wds;
        float a = 0.f;
#pragma unroll 4
        for (int q2 = 0; q2 < 256; ++q2) a = fmaf(dhv[q2], W[q2 * 128 + i_], a);
        if (tid < 128) dmv[i_] = a; else dsv[i_] = softplusf_(a);
    }
    if (tid < 128) {
        const int m = tid & 63;
        const float* W = (tid < 64) ? Wpzm : Wpzs;
        float a = 0.f;
#pragma unroll 4
        for (int q2 = 0; q2 < 256; ++q2) a = fmaf(pzh[q2], W[q2 * 64 + m], a);
        if (tid < 64) pmv[m] = a; else psv[m] = softplusf_(a);
    }
    __syncthreads();

    float kldc = 0.f, recc = 0.f;
    if (tid < 64) {
        float es = esv[tid], em = emv[tid], pm = pmv[tid], ps = psv[tid];
        float d = em - pm;
        kldc = __logf(ps / es) + (es * es + d * d) / (2.f * ps * ps) - 0.5f;
    }
    if (tid < 128) {
        float dm = dmv[tid], ds = dsv[tid], xv = xcv[tid];
        float d = xv - dm;
        recc = CC + __logf(ds) + d * d / (2.f * ds * ds);
    }

#pragma unroll
    for (int d = 1; d < 64; d <<= 1) {
        cp += __shfl_xor(cp, d);
        cq += __shfl_xor(cq, d);
        kldc += __shfl_xor(kldc, d);
        recc += __shfl_xor(recc, d);
    }
    if ((tid & 63) == 0) {
        const int w = tid >> 6;
        rl[w * 4 + 0] = cp; rl[w * 4 + 1] = cq;
        rl[w * 4 + 2] = kldc; rl[w * 4 + 3] = recc;
    }
    __syncthreads();
    if (tid == 0) {
        float plog = rl[0] + rl[4] + rl[8]  + rl[12];
        float qlog = rl[1] + rl[5] + rl[9]  + rl[13];
        float kld  = rl[2] + rl[6] + rl[10] + rl[14];
        float rec  = rl[3] + rl[7] + rl[11] + rl[15];
        float p = sigmoidf_(plog), q = sigmoidf_(qlog);
        float bce  = -(y_t * __logf(p) + (1.f - y_t) * __logf(1.f - p));
        float addt = y_t * __logf(p * q) + (1.f - y_t) * __logf((1.f - p) * (1.f - q));
        float kcat = p * __logf(p / q) + (1.f - p) * __logf((1.f - p) / (1.f - q));
        float ul = 1.f - lf;
        float* pr = part + (size_t)t * 7;
        pr[0] = lf * kld;  pr[1] = lf * rec;  pr[2] = lf * bce;
        pr[3] = ul * kld;  pr[4] = ul * rec;  pr[5] = ul * kcat;
        pr[6] = lf * addt;
    }
}

__global__ __launch_bounds__(256) void k_final(const float* __restrict__ part,
                                               float* __restrict__ out)
{
    const int o = blockIdx.x;
    float s = 0.f;
    for (int b = threadIdx.x; b < T; b += 256) s += part[(size_t)b * 7 + o];
#pragma unroll
    for (int d = 1; d < 64; d <<= 1) s += __shfl_xor(s, d);
    __shared__ float l[4];
    if ((threadIdx.x & 63) == 0) l[threadIdx.x >> 6] = s;
    __syncthreads();
    if (threadIdx.x == 0) out[o] = (l[0] + l[1]) + (l[2] + l[3]);
}

extern "C" void kernel_launch(void* const* d_in, const int* in_sizes, int n_in,
                              void* d_out, int out_size, void* d_ws, size_t ws_size,
                              hipStream_t stream) {
    (void)in_sizes; (void)n_in; (void)out_size; (void)ws_size;
    const float* x    = (const float*)d_in[0];
    const float* yin  = (const float*)d_in[1];
    const float* ez   = (const float*)d_in[2];
    const float* eu   = (const float*)d_in[3];
    const float* Wpz  = (const float*)d_in[4];
    const float* Wpzm = (const float*)d_in[5];
    const float* Wpzs = (const float*)d_in[6];
    const float* Wpy  = (const float*)d_in[7];
    const float* ppr  = (const float*)d_in[8];
    const float* Wqy  = (const float*)d_in[9];
    const float* qpr  = (const float*)d_in[10];
    const float* Wenc = (const float*)d_in[11];
    const float* Wem  = (const float*)d_in[12];
    const float* Wes  = (const float*)d_in[13];
    const float* Wd   = (const float*)d_in[14];
    const float* Wdm  = (const float*)d_in[15];
    const float* Wds  = (const float*)d_in[16];
    const float* Wih  = (const float*)d_in[17];
    const float* Whh  = (const float*)d_in[18];

    float* ws = (float*)d_ws;
    float* Aq    = ws;                           // T*256
    float* Ae    = Aq    + (size_t)T * 256;      // T*256
    float* Ah    = Ae    + (size_t)T * 256;      // T*128
    float* h_st  = Ah    + (size_t)T * 128;      // T*128
    float* z_st  = h_st  + (size_t)T * 128;      // T*64
    float* em_st = z_st  + (size_t)T * 64;       // T*64
    float* es_st = em_st + (size_t)T * 64;       // T*64
    float* y_st  = es_st + (size_t)T * 64;       // T
    float* part  = y_st  + (size_t)T;            // T*7
    float* leu   = part  + (size_t)T * 7;        // T

    k_pre<<<T / 16, 256, 0, stream>>>(x, eu, Wqy, Wenc, Wih, Aq, Ae, Ah, leu);
    k_scan<<<1, 512, 0, stream>>>(Wqy, qpr, Wenc, Wem, Wes, Wih, Whh,
                                  yin, leu, ez, Aq, Ae, Ah,
                                  h_st, z_st, em_st, es_st, y_st);
    k_post<<<T, 256, 0, stream>>>(x, yin, Wpz, Wpzm, Wpzs, Wpy, ppr, Wqy, qpr,
                                  Wd, Wdm, Wds, Aq, h_st, z_st, em_st, es_st,
                                  y_st, part);
    k_final<<<7, 256, 0, stream>>>(part, (float*)d_out);
}